// Round 13
// baseline (459.294 us; speedup 1.0000x reference)
//
#include <hip/hip_runtime.h>

typedef unsigned short u16;
typedef __attribute__((ext_vector_type(4))) float f32x4;
typedef __attribute__((ext_vector_type(8))) __bf16 bf16x8;
typedef __attribute__((ext_vector_type(8))) u16 u16x8;

#define ALPHA_F 0.1f

// Cl(3,0): e_a * e_c = (-1)^p e_{a^c}  [validated R1-R12]
__device__ __host__ constexpr bool SGN(int a, int c) {
  return ((((c & 1) & (((a >> 1) ^ (a >> 2)) & 1)) ^
           (((c >> 1) & 1) & ((a >> 2) & 1))) != 0);
}
__device__ __host__ constexpr float REVF(int c) {
  const int r = (c & 1) + ((c >> 1) & 1) + ((c >> 2) & 1);
  return (r >= 2) ? -1.f : 1.f;
}
__device__ __forceinline__ u16 bf_rnd(float f) {
  unsigned u = __float_as_uint(f);
  return (u16)((u + 0x7FFFu + ((u >> 16) & 1u)) >> 16);
}
__device__ __forceinline__ float bf_val(u16 h) {
  return __uint_as_float(((unsigned)h) << 16);
}
__device__ __forceinline__ f32x4 mf(bf16x8 a, bf16x8 b, f32x4 c) {
  return __builtin_amdgcn_mfma_f32_16x16x32_bf16(a, b, c, 0, 0, 0);
}
__device__ __forceinline__ bf16x8 negf(bf16x8 v) {
  u16x8 u = __builtin_bit_cast(u16x8, v);
  const u16x8 m = {0x8000, 0x8000, 0x8000, 0x8000, 0x8000, 0x8000, 0x8000, 0x8000};
  u = u ^ m;
  return __builtin_bit_cast(bf16x8, u);
}

// ===========================================================================
// D1: pack raw inputs (validated R10-R12). UNCHANGED.
// ===========================================================================
__global__ __launch_bounds__(256) void pack_in(
    const float* __restrict__ x, const float* __restrict__ w1,
    const float* __restrict__ w2, u16* P1h, u16* P1l, u16* Q1, u16* Qc1,
    u16* P2h, u16* P2l, u16* Q2, u16* Axh, u16* Axl, u16* Vpk2, u16* Z0h,
    u16* Z0l, float* out0) {
  const int t = blockIdx.x * 256 + threadIdx.x;
  if (t < 131072) {  // Q1 + Qc1 (cc-fast): r = m, cc = n'
    const int r = t >> 9, cc = t & 511;
    const float* s = w1 + ((size_t)r * 512 + cc) * 8;
    float v[8];
#pragma unroll
    for (int c = 0; c < 8; ++c) v[c] = s[c];
    const size_t qo = (size_t)((cc >> 4) * 2 + (r >> 7)) * 32768 +
                      ((r >> 5) & 3) * 512 + ((r >> 3) & 3) * 128 +
                      (cc & 15) * 8 + (r & 7);
#pragma unroll
    for (int c = 0; c < 8; ++c) {
      const float q1 = REVF(c) * v[c];
      u16 h = bf_rnd(q1);
      Q1[qo + c * 4096] = h;
      Q1[qo + c * 4096 + 2048] = bf_rnd(q1 - bf_val(h));
      const float qc = ALPHA_F * q1;
      h = bf_rnd(qc);
      Qc1[qo + c * 4096] = h;
      Qc1[qo + c * 4096 + 2048] = bf_rnd(qc - bf_val(h));
    }
  } else if (t < 262144) {  // Q2 + Wcat-bottom (c2-fast): r = m, c2 = j
    const int u = t - 131072;
    const int r = u >> 8, c2 = u & 255;
    const float* s = w2 + ((size_t)r * 256 + c2) * 8;
    float v[8];
#pragma unroll
    for (int c = 0; c < 8; ++c) v[c] = s[c];
    const size_t tail = ((r >> 5) & 3) * 512 + ((r >> 3) & 3) * 128 +
                        (c2 & 15) * 8 + (r & 7);
    const size_t qo = (size_t)((c2 >> 4) * 4 + (r >> 7)) * 32768 + tail;
    const size_t wo = (size_t)((c2 >> 4) * 6 + 2 + (r >> 7)) * 32768 + tail;
#pragma unroll
    for (int c = 0; c < 8; ++c) {
      const float q2 = REVF(c) * v[c];
      u16 h = bf_rnd(q2);
      Q2[qo + c * 4096] = h;
      Q2[qo + c * 4096 + 2048] = bf_rnd(q2 - bf_val(h));
      const float qw = ALPHA_F * q2;
      h = bf_rnd(qw);
      Vpk2[wo + c * 4096] = h;
      Vpk2[wo + c * 4096 + 2048] = bf_rnd(qw - bf_val(h));
    }
  } else if (t < 393216) {  // P1c chunk planes [a][m>>3][n'][m&7]
    const int u = t - 262144;
    const int r = u & 255, cc = u >> 8;
    const float* s = w1 + ((size_t)r * 512 + cc) * 8;
#pragma unroll
    for (int a = 0; a < 8; ++a) {
      const float v = s[a];
      const u16 h = bf_rnd(v);
      const size_t o = ((size_t)(a * 32 + (r >> 3)) * 512 + cc) * 8 + (r & 7);
      P1h[o] = h;
      P1l[o] = bf_rnd(v - bf_val(h));
    }
  } else if (t < 524288) {  // P2c chunk planes [a][m>>3][j][m&7]
    const int u = t - 393216;
    const int r = u & 511, c2 = u >> 9;
    const float* s = w2 + ((size_t)r * 256 + c2) * 8;
#pragma unroll
    for (int a = 0; a < 8; ++a) {
      const float v = s[a];
      const u16 h = bf_rnd(v);
      const size_t o = ((size_t)(a * 64 + (r >> 3)) * 256 + c2) * 8 + (r & 7);
      P2h[o] = h;
      P2l[o] = bf_rnd(v - bf_val(h));
    }
  } else if (t < 540672) {  // Axc chunk planes [a][n>>3][b][n&7]
    const int u = t - 524288;
    const int b = u >> 8, n = u & 255;
    const float* s = x + ((size_t)b * 256 + n) * 8;
#pragma unroll
    for (int a = 0; a < 8; ++a) {
      const u16 h = bf_rnd(s[a]);
      const size_t o = ((size_t)(a * 32 + (n >> 3)) * 64 + b) * 8 + (n & 7);
      Axh[o] = h;
      Axl[o] = bf_rnd(s[a] - bf_val(h));
    }
  } else if (t < 573440) {  // out0 = x
    const int u = t - 540672;
    ((float4*)out0)[u] = ((const float4*)x)[u];
  } else if (t < 606208) {  // Z0 S2-region zero
    const int u = t - 573440;
    const int hl = u >> 14, i = u & 16383;
    const int a = i >> 11, j = i & 2047;
    const u16x8 z = {0, 0, 0, 0, 0, 0, 0, 0};
    u16* Z = hl ? Z0l : Z0h;
    *(u16x8*)&Z[(size_t)a * 49152 + (size_t)j * 8] = z;
  }
}

// ===========================================================================
// D2: composeK (validated R11/R12). UNCHANGED.
// ===========================================================================
__global__ __launch_bounds__(512, 2) void composeK(
    const u16* __restrict__ P1h, const u16* __restrict__ P1l,
    const u16* __restrict__ Q1, const u16* __restrict__ P2h,
    const u16* __restrict__ P2l, const u16* __restrict__ Q2,
    const u16* __restrict__ Axh, const u16* __restrict__ Axl,
    const u16* __restrict__ Qc1, u16* Vpk1, u16* Vpk2, u16* Z0h, u16* Z0l,
    float* c1Z) {
  __shared__ float pan[8][2176];

  const int bid = blockIdx.x, tid = threadIdx.x;
  const int w = tid >> 6, l = tid & 63;
  const int lg = l >> 4, lm = l & 15;

  int seg, rb, p;
  if (bid < 256) { seg = 1; rb = bid & 15; p = bid >> 4; }
  else if (bid < 1280) { seg = 0; rb = (bid - 256) & 31; p = (bid - 256) >> 5; }
  else { seg = 2; rb = (bid - 1280) & 3; p = (bid - 1280) >> 2; }

  const u16* Ah_ = seg == 0 ? P1h : (seg == 1 ? P2h : Axh);
  const u16* Al_ = seg == 0 ? P1l : (seg == 1 ? P2l : Axl);
  const u16* Vb = seg == 0 ? Q1 : (seg == 1 ? Q2 : Qc1);
  const int NROW = seg == 0 ? 512 : (seg == 1 ? 256 : 64);
  const int KC = seg == 1 ? 64 : 32;
  const int NW = seg == 1 ? 2 : 1;
  const int slmul = seg == 1 ? 4 : 2;
  const int row = rb * 16 + lm;

  f32x4 acc[8];
#pragma unroll
  for (int k = 0; k < 8; ++k) acc[k] = f32x4{0.f, 0.f, 0.f, 0.f};

  for (int wi = 0; wi < NW; ++wi) {
    const int n0 = w * (NW * 32) + wi * 32;
    const int sl = n0 >> 7, hst = (n0 >> 5) & 3;
    const u16* Vimg =
        Vb + ((size_t)(p * slmul + sl) << 15) + hst * 512 + lg * 128 + lm * 8;
    const int kc = (n0 >> 3) + lg;
    bf16x8 ah[8], al[8];
#pragma unroll
    for (int a = 0; a < 8; ++a) {
      const size_t o = ((size_t)(a * KC + kc) * NROW + row) * 8;
      ah[a] = *(const bf16x8*)(Ah_ + o);
      al[a] = *(const bf16x8*)(Al_ + o);
    }
    __builtin_amdgcn_s_setprio(1);
#pragma unroll
    for (int c = 0; c < 8; ++c) {
      const bf16x8 vhp = *(const bf16x8*)(Vimg + (size_t)c * 4096);
      const bf16x8 vlp = *(const bf16x8*)(Vimg + (size_t)c * 4096 + 2048);
      const bf16x8 vhn = negf(vhp), vln = negf(vlp);
#pragma unroll
      for (int a = 0; a < 8; ++a) {
        const int k = a ^ c;
        const bf16x8 vh = SGN(a, c) ? vhn : vhp;
        const bf16x8 vl = SGN(a, c) ? vln : vlp;
        acc[k] = mf(ah[a], vh, acc[k]);
        acc[k] = mf(al[a], vh, acc[k]);
        acc[k] = mf(ah[a], vl, acc[k]);
      }
    }
    __builtin_amdgcn_s_setprio(0);
  }

#pragma unroll
  for (int k = 0; k < 8; ++k)
#pragma unroll
    for (int q = 0; q < 4; ++q)
      pan[w][(k * 16 + lg * 4 + q) * 17 + lm] = acc[k][q];
  __syncthreads();

  if (tid < 256) {
    const int k = tid >> 5, rw = (tid >> 1) & 15, ch = tid & 1;
    const int boff = (k * 16 + rw) * 17 + ch * 8;
    f32x4 s0 = {0.f, 0.f, 0.f, 0.f}, s1 = {0.f, 0.f, 0.f, 0.f};
    for (int ss = 0; ss < 8; ++ss) {
      s0 += *(const f32x4*)&pan[ss][boff];
      s1 += *(const f32x4*)&pan[ss][boff + 4];
    }
    float v[8];
#pragma unroll
    for (int e = 0; e < 4; ++e) { v[e] = s0[e]; v[4 + e] = s1[e]; }
    const int n = rb * 16 + rw;

    if (seg <= 1) {
      u16* base = seg == 0 ? Vpk1 : Vpk2;
      const int blk = (seg == 0 ? p * 4 : p * 6) + (n >> 7);
      u16* d = base + ((size_t)blk << 15) + (size_t)k * 4096 +
               ((n >> 5) & 3) * 512 + ((n >> 3) & 3) * 128 + (n & 7);
#pragma unroll
      for (int e = 0; e < 8; ++e) {
        const int m = p * 16 + ch * 8 + e;
        const float val = ((k == 0) && (n == m) ? 1.0f : 0.0f) - ALPHA_F * v[e];
        const u16 hh = bf_rnd(val);
        d[(size_t)(ch * 8 + e) * 8] = hh;
        d[2048 + (size_t)(ch * 8 + e) * 8] = bf_rnd(val - bf_val(hh));
      }
    } else {
      const int b = n;
      float* cp_ = c1Z + (((size_t)k * 64 + p * 2 + ch) * 64 + b) * 8;
      u16x8 h8, l8;
#pragma unroll
      for (int e = 0; e < 8; ++e) {
        cp_[e] = v[e];
        const u16 hh = bf_rnd(v[e]);
        h8[e] = hh;
        l8[e] = bf_rnd(v[e] - bf_val(hh));
      }
      const size_t zo = (((size_t)k * 96 + 32 + p * 2 + ch) * 64 + b) * 8;
      *(u16x8*)&Z0h[zo] = h8;
      *(u16x8*)&Z0l[zo] = l8;
    }
  }
}

// ===========================================================================
// Main-loop pair kernel — 1024-thread / 16-wave blocks for 4 waves/SIMD TLP.
// Each wave owns K-32 window(s): g1 wave w -> window w (16x32=512).
// g2: waves 0..7 -> windows {2w,2w+1}, waves 8..15 -> window w+8 (24 total;
// per-SIMD balanced: 6 windows each). Two-phase deterministic LDS merge:
// waves 8..15 add into slots 0..7, then 8-slot fixed-order sum.
// ===========================================================================
struct IArgs {
  const u16 *Zch, *Zcl;
  u16 *Znh, *Znl;
  const u16 *Vpk1, *Vpk2;
  const float* c1Z;
  float *out1, *out2;
  int n_g1;
};

template <bool G1>
__device__ __forceinline__ void iter_body(const IArgs& A, int t18, int fin,
                                          float (*pan)[2176]) {
  const int bid = blockIdx.x, tid = threadIdx.x;
  const int w = tid >> 6, l = tid & 63;
  const int lg = l >> 4, lm = l & 15;
  const int rb = G1 ? bid : bid - A.n_g1;
  constexpr int NPAN = G1 ? 32 : 16;
  const int p = rb & (NPAN - 1);  // XCD-affine (R10)
  const int bh = rb / NPAN;
  const int b0 = bh * 16;
  constexpr int acb0 = G1 ? 32 : 0;
  constexpr int slmul = G1 ? 4 : 6;
  const u16* Vb = G1 ? A.Vpk1 : A.Vpk2;

  f32x4 acc[8];
#pragma unroll
  for (int k = 0; k < 8; ++k) acc[k] = f32x4{0.f, 0.f, 0.f, 0.f};

  auto DOWIN = [&](int widx) {
    const int n0 = widx * 32;
    const size_t ao = ((size_t)(acb0 + (n0 >> 3) + lg) * 64 + b0 + lm) * 8;
    bf16x8 ah[8], al[8];
#pragma unroll
    for (int a = 0; a < 8; ++a) {
      ah[a] = *(const bf16x8*)(A.Zch + (size_t)a * 49152 + ao);
      al[a] = *(const bf16x8*)(A.Zcl + (size_t)a * 49152 + ao);
    }
    const int sl = n0 >> 7, hst = (n0 >> 5) & 3;
    const u16* Vimg = Vb + ((size_t)(p * slmul + sl) << 15) + hst * 512 +
                      lg * 128 + lm * 8;
    __builtin_amdgcn_s_setprio(1);
#pragma unroll
    for (int c = 0; c < 8; ++c) {
      const bf16x8 vhp = *(const bf16x8*)(Vimg + (size_t)c * 4096);
      const bf16x8 vlp = *(const bf16x8*)(Vimg + (size_t)c * 4096 + 2048);
      const bf16x8 vhn = negf(vhp), vln = negf(vlp);
#pragma unroll
      for (int a = 0; a < 8; ++a) {
        const int k = a ^ c;
        const bf16x8 vh = SGN(a, c) ? vhn : vhp;
        const bf16x8 vl = SGN(a, c) ? vln : vlp;
        acc[k] = mf(ah[a], vh, acc[k]);
        acc[k] = mf(al[a], vh, acc[k]);
        acc[k] = mf(ah[a], vl, acc[k]);
      }
    }
    __builtin_amdgcn_s_setprio(0);
  };

  if constexpr (G1) {
    DOWIN(w);
  } else {
    if (w < 8) {
      DOWIN(2 * w);
      DOWIN(2 * w + 1);
    } else {
      DOWIN(w + 8);
    }
  }

  // two-phase deterministic merge into 8 LDS slots
  if (w < 8) {
#pragma unroll
    for (int k = 0; k < 8; ++k)
#pragma unroll
      for (int q = 0; q < 4; ++q)
        pan[w][(k * 16 + lg * 4 + q) * 17 + lm] = acc[k][q];
  }
  __syncthreads();
  if (w >= 8) {
#pragma unroll
    for (int k = 0; k < 8; ++k)
#pragma unroll
      for (int q = 0; q < 4; ++q)
        pan[w - 8][(k * 16 + lg * 4 + q) * 17 + lm] += acc[k][q];
  }
  __syncthreads();

  if (tid < 256) {
    const int k = tid >> 5, row = (tid >> 1) & 15, ch = tid & 1;
    const int boff = (k * 16 + row) * 17 + ch * 8;
    f32x4 s0 = {0.f, 0.f, 0.f, 0.f}, s1 = {0.f, 0.f, 0.f, 0.f};
    for (int ss = 0; ss < 8; ++ss) {
      s0 += *(const f32x4*)&pan[ss][boff];
      s1 += *(const f32x4*)&pan[ss][boff + 4];
    }
    const int b = b0 + row;
    if constexpr (G1) {
      const float* ca = A.c1Z + (((size_t)k * 64 + p * 2 + ch) * 64 + b) * 8;
      s0 += *(const f32x4*)ca;
      s1 += *(const f32x4*)(ca + 4);
    }
    float v[8];
#pragma unroll
    for (int e = 0; e < 4; ++e) { v[e] = s0[e]; v[4 + e] = s1[e]; }
    if (!fin) {
      u16x8 h8, l8;
#pragma unroll
      for (int e = 0; e < 8; ++e) {
        const u16 hh = bf_rnd(v[e]);
        h8[e] = hh;
        l8[e] = bf_rnd(v[e] - bf_val(hh));
      }
      const size_t zo =
          (((size_t)k * 96 + (G1 ? 32 : 0) + p * 2 + ch) * 64 + b) * 8;
      *(u16x8*)&A.Znh[zo] = h8;
      *(u16x8*)&A.Znl[zo] = l8;
    }
    if constexpr (G1) {
      if (t18) {
#pragma unroll
        for (int e = 0; e < 8; ++e)
          A.out1[((size_t)b * 512 + p * 16 + ch * 8 + e) * 8 + k] = v[e];
      }
    } else {
      if (fin) {
#pragma unroll
        for (int e = 0; e < 8; ++e)
          A.out2[((size_t)b * 256 + p * 16 + ch * 8 + e) * 8 + k] = v[e];
      }
    }
  }
}

__global__ __launch_bounds__(1024, 4) void iter_k(IArgs A, int t18, int fin) {
  __shared__ float pan[8][2176];
  if ((int)blockIdx.x < A.n_g1) iter_body<true>(A, t18, fin, pan);
  else iter_body<false>(A, t18, fin, pan);
}

extern "C" void kernel_launch(void* const* d_in, const int* in_sizes, int n_in,
                              void* d_out, int out_size, void* d_ws,
                              size_t ws_size, hipStream_t stream) {
  const float* x = (const float*)d_in[0];
  const float* w1 = (const float*)d_in[1];
  const float* w2 = (const float*)d_in[2];

  float* out0 = (float*)d_out;
  float* out1 = out0 + 131072;
  float* out2 = out1 + 262144;

  char* W = (char*)d_ws;
  const size_t MB = 1ull << 20;
  u16* Vpk1 = (u16*)(W);
  u16* Vpk2 = (u16*)(W + 8 * MB);
  u16* Q1 = (u16*)(W + 14 * MB);
  u16* Q2 = (u16*)(W + 18 * MB);
  u16* Qc1 = (u16*)(W + 22 * MB);
  u16* P1h = (u16*)(W + 26 * MB);
  u16* P1l = (u16*)(W + 28 * MB);
  u16* P2h = (u16*)(W + 30 * MB);
  u16* P2l = (u16*)(W + 32 * MB);
  u16* Axh = (u16*)(W + 34 * MB);
  u16* Axl = (u16*)(W + 34 * MB + 262144);
  float* c1Z = (float*)(W + 35 * MB);
  u16* Z0h = (u16*)(W + 46 * MB);
  u16* Z0l = Z0h + 393216;
  u16* Z1h = Z0h + 786432;
  u16* Z1l = Z0h + 1179648;

  // D1: pack raw inputs
  pack_in<<<2368, 256, 0, stream>>>(x, w1, w2, P1h, P1l, Q1, Qc1, P2h, P2l, Q2,
                                    Axh, Axl, Vpk2, Z0h, Z0l, out0);

  // D2: compose + fused operator pack
  composeK<<<1408, 512, 0, stream>>>(P1h, P1l, Q1, P2h, P2l, Q2, Axh, Axl, Qc1,
                                     Vpk1, Vpk2, Z0h, Z0l, c1Z);

  // D3..D21: 19 stream-ordered pair dispatches {g2_t, g1_{t+1}}
  for (int t = 0; t < 19; ++t) {
    IArgs ia;
    ia.Zch = (t & 1) ? Z1h : Z0h;
    ia.Zcl = (t & 1) ? Z1l : Z0l;
    ia.Znh = (t & 1) ? Z0h : Z1h;
    ia.Znl = (t & 1) ? Z0l : Z1l;
    ia.Vpk1 = Vpk1; ia.Vpk2 = Vpk2; ia.c1Z = c1Z;
    ia.out1 = out1; ia.out2 = nullptr;
    ia.n_g1 = 128;
    iter_k<<<192, 1024, 0, stream>>>(ia, t == 18 ? 1 : 0, 0);
  }

  // D22: final g2_19 reads Z1 = [S2_19 | S1_20] -> out2 = S2_20
  {
    IArgs ia;
    ia.Zch = Z1h; ia.Zcl = Z1l;
    ia.Znh = Z0h; ia.Znl = Z0l;  // unused (fin)
    ia.Vpk1 = Vpk1; ia.Vpk2 = Vpk2; ia.c1Z = c1Z;
    ia.out1 = out1; ia.out2 = out2;
    ia.n_g1 = 0;
    iter_k<<<64, 1024, 0, stream>>>(ia, 0, 1);
  }
}

// Round 14
// 363.004 us; speedup vs baseline: 1.2653x; 1.2653x over previous
//
#include <hip/hip_runtime.h>

typedef unsigned short u16;
typedef __attribute__((ext_vector_type(4))) float f32x4;
typedef __attribute__((ext_vector_type(8))) __bf16 bf16x8;
typedef __attribute__((ext_vector_type(8))) u16 u16x8;

#define ALPHA_F 0.1f

// Cl(3,0): e_a * e_c = (-1)^p e_{a^c}  [validated R1-R13]
__device__ __host__ constexpr bool SGN(int a, int c) {
  return ((((c & 1) & (((a >> 1) ^ (a >> 2)) & 1)) ^
           (((c >> 1) & 1) & ((a >> 2) & 1))) != 0);
}
__device__ __host__ constexpr float REVF(int c) {
  const int r = (c & 1) + ((c >> 1) & 1) + ((c >> 2) & 1);
  return (r >= 2) ? -1.f : 1.f;
}
__device__ __forceinline__ u16 bf_rnd(float f) {
  unsigned u = __float_as_uint(f);
  return (u16)((u + 0x7FFFu + ((u >> 16) & 1u)) >> 16);
}
__device__ __forceinline__ float bf_val(u16 h) {
  return __uint_as_float(((unsigned)h) << 16);
}
__device__ __forceinline__ f32x4 mf(bf16x8 a, bf16x8 b, f32x4 c) {
  return __builtin_amdgcn_mfma_f32_16x16x32_bf16(a, b, c, 0, 0, 0);
}
__device__ __forceinline__ bf16x8 negf(bf16x8 v) {
  u16x8 u = __builtin_bit_cast(u16x8, v);
  const u16x8 m = {0x8000, 0x8000, 0x8000, 0x8000, 0x8000, 0x8000, 0x8000, 0x8000};
  u = u ^ m;
  return __builtin_bit_cast(bf16x8, u);
}

// ===========================================================================
// D1: pack raw inputs (validated R10-R13) + NEW: B-plane emission
// (B[n1,j] = alpha*rev(w2), A-operand chunk-plane form for compose2).
// ===========================================================================
__global__ __launch_bounds__(256) void pack_in(
    const float* __restrict__ x, const float* __restrict__ w1,
    const float* __restrict__ w2, u16* P1h, u16* P1l, u16* Q1, u16* Qc1,
    u16* P2h, u16* P2l, u16* Q2, u16* Axh, u16* Axl, u16* Vpk2,
    u16* BpAh, u16* BpAl, u16* Z0h, u16* Z0l, float* out0) {
  const int t = blockIdx.x * 256 + threadIdx.x;
  if (t < 131072) {  // Q1 + Qc1 (cc-fast): r = m, cc = n'
    const int r = t >> 9, cc = t & 511;
    const float* s = w1 + ((size_t)r * 512 + cc) * 8;
    float v[8];
#pragma unroll
    for (int c = 0; c < 8; ++c) v[c] = s[c];
    const size_t qo = (size_t)((cc >> 4) * 2 + (r >> 7)) * 32768 +
                      ((r >> 5) & 3) * 512 + ((r >> 3) & 3) * 128 +
                      (cc & 15) * 8 + (r & 7);
#pragma unroll
    for (int c = 0; c < 8; ++c) {
      const float q1 = REVF(c) * v[c];
      u16 h = bf_rnd(q1);
      Q1[qo + c * 4096] = h;
      Q1[qo + c * 4096 + 2048] = bf_rnd(q1 - bf_val(h));
      const float qc = ALPHA_F * q1;
      h = bf_rnd(qc);
      Qc1[qo + c * 4096] = h;
      Qc1[qo + c * 4096 + 2048] = bf_rnd(qc - bf_val(h));
    }
  } else if (t < 262144) {  // Q2 + Wcat-bottom + B-planes: r = m(512), c2 = j
    const int u = t - 131072;
    const int r = u >> 8, c2 = u & 255;
    const float* s = w2 + ((size_t)r * 256 + c2) * 8;
    float v[8];
#pragma unroll
    for (int c = 0; c < 8; ++c) v[c] = s[c];
    const size_t tail = ((r >> 5) & 3) * 512 + ((r >> 3) & 3) * 128 +
                        (c2 & 15) * 8 + (r & 7);
    const size_t qo = (size_t)((c2 >> 4) * 4 + (r >> 7)) * 32768 + tail;
    const size_t wo = (size_t)((c2 >> 4) * 6 + 2 + (r >> 7)) * 32768 + tail;
#pragma unroll
    for (int c = 0; c < 8; ++c) {
      const float q2 = REVF(c) * v[c];
      u16 h = bf_rnd(q2);
      Q2[qo + c * 4096] = h;
      Q2[qo + c * 4096 + 2048] = bf_rnd(q2 - bf_val(h));
      const float qw = ALPHA_F * q2;
      h = bf_rnd(qw);
      const u16 lo = bf_rnd(qw - bf_val(h));
      Vpk2[wo + c * 4096] = h;
      Vpk2[wo + c * 4096 + 2048] = lo;
      // B-plane (A-operand form): [c][j-chunk][n1=r][j&7]
      const size_t bo = ((size_t)(c * 32 + (c2 >> 3)) * 512 + r) * 8 + (c2 & 7);
      BpAh[bo] = h;
      BpAl[bo] = lo;
    }
  } else if (t < 393216) {  // P1c chunk planes
    const int u = t - 262144;
    const int r = u & 255, cc = u >> 8;
    const float* s = w1 + ((size_t)r * 512 + cc) * 8;
#pragma unroll
    for (int a = 0; a < 8; ++a) {
      const float v = s[a];
      const u16 h = bf_rnd(v);
      const size_t o = ((size_t)(a * 32 + (r >> 3)) * 512 + cc) * 8 + (r & 7);
      P1h[o] = h;
      P1l[o] = bf_rnd(v - bf_val(h));
    }
  } else if (t < 524288) {  // P2c chunk planes
    const int u = t - 393216;
    const int r = u & 511, c2 = u >> 9;
    const float* s = w2 + ((size_t)r * 256 + c2) * 8;
#pragma unroll
    for (int a = 0; a < 8; ++a) {
      const float v = s[a];
      const u16 h = bf_rnd(v);
      const size_t o = ((size_t)(a * 64 + (r >> 3)) * 256 + c2) * 8 + (r & 7);
      P2h[o] = h;
      P2l[o] = bf_rnd(v - bf_val(h));
    }
  } else if (t < 540672) {  // Axc chunk planes
    const int u = t - 524288;
    const int b = u >> 8, n = u & 255;
    const float* s = x + ((size_t)b * 256 + n) * 8;
#pragma unroll
    for (int a = 0; a < 8; ++a) {
      const u16 h = bf_rnd(s[a]);
      const size_t o = ((size_t)(a * 32 + (n >> 3)) * 64 + b) * 8 + (n & 7);
      Axh[o] = h;
      Axl[o] = bf_rnd(s[a] - bf_val(h));
    }
  } else if (t < 573440) {  // out0 = x
    const int u = t - 540672;
    ((float4*)out0)[u] = ((const float4*)x)[u];
  } else if (t < 606208) {  // Z0 S2-region zero
    const int u = t - 573440;
    const int hl = u >> 14, i = u & 16383;
    const int a = i >> 11, j = i & 2047;
    const u16x8 z = {0, 0, 0, 0, 0, 0, 0, 0};
    u16* Z = hl ? Z0l : Z0h;
    *(u16x8*)&Z[(size_t)a * 49152 + (size_t)j * 8] = z;
  }
}

// ===========================================================================
// D2: composeK (validated R11-R13) + NEW: A-plane emissions of the packed
// operators (V1~ planes, U planes) for compose2.
// ===========================================================================
__global__ __launch_bounds__(512, 2) void composeK(
    const u16* __restrict__ P1h, const u16* __restrict__ P1l,
    const u16* __restrict__ Q1, const u16* __restrict__ P2h,
    const u16* __restrict__ P2l, const u16* __restrict__ Q2,
    const u16* __restrict__ Axh, const u16* __restrict__ Axl,
    const u16* __restrict__ Qc1, u16* Vpk1, u16* Vpk2,
    u16* V1pAh, u16* V1pAl, u16* UpAh, u16* UpAl,
    u16* Z0h, u16* Z0l, float* c1Z) {
  __shared__ float pan[8][2176];

  const int bid = blockIdx.x, tid = threadIdx.x;
  const int w = tid >> 6, l = tid & 63;
  const int lg = l >> 4, lm = l & 15;

  int seg, rb, p;
  if (bid < 256) { seg = 1; rb = bid & 15; p = bid >> 4; }
  else if (bid < 1280) { seg = 0; rb = (bid - 256) & 31; p = (bid - 256) >> 5; }
  else { seg = 2; rb = (bid - 1280) & 3; p = (bid - 1280) >> 2; }

  const u16* Ah_ = seg == 0 ? P1h : (seg == 1 ? P2h : Axh);
  const u16* Al_ = seg == 0 ? P1l : (seg == 1 ? P2l : Axl);
  const u16* Vb = seg == 0 ? Q1 : (seg == 1 ? Q2 : Qc1);
  const int NROW = seg == 0 ? 512 : (seg == 1 ? 256 : 64);
  const int KC = seg == 1 ? 64 : 32;
  const int NW = seg == 1 ? 2 : 1;
  const int slmul = seg == 1 ? 4 : 2;
  const int row = rb * 16 + lm;

  f32x4 acc[8];
#pragma unroll
  for (int k = 0; k < 8; ++k) acc[k] = f32x4{0.f, 0.f, 0.f, 0.f};

  for (int wi = 0; wi < NW; ++wi) {
    const int n0 = w * (NW * 32) + wi * 32;
    const int sl = n0 >> 7, hst = (n0 >> 5) & 3;
    const u16* Vimg =
        Vb + ((size_t)(p * slmul + sl) << 15) + hst * 512 + lg * 128 + lm * 8;
    const int kc = (n0 >> 3) + lg;
    bf16x8 ah[8], al[8];
#pragma unroll
    for (int a = 0; a < 8; ++a) {
      const size_t o = ((size_t)(a * KC + kc) * NROW + row) * 8;
      ah[a] = *(const bf16x8*)(Ah_ + o);
      al[a] = *(const bf16x8*)(Al_ + o);
    }
    __builtin_amdgcn_s_setprio(1);
#pragma unroll
    for (int c = 0; c < 8; ++c) {
      const bf16x8 vhp = *(const bf16x8*)(Vimg + (size_t)c * 4096);
      const bf16x8 vlp = *(const bf16x8*)(Vimg + (size_t)c * 4096 + 2048);
      const bf16x8 vhn = negf(vhp), vln = negf(vlp);
#pragma unroll
      for (int a = 0; a < 8; ++a) {
        const int k = a ^ c;
        const bf16x8 vh = SGN(a, c) ? vhn : vhp;
        const bf16x8 vl = SGN(a, c) ? vln : vlp;
        acc[k] = mf(ah[a], vh, acc[k]);
        acc[k] = mf(al[a], vh, acc[k]);
        acc[k] = mf(ah[a], vl, acc[k]);
      }
    }
    __builtin_amdgcn_s_setprio(0);
  }

#pragma unroll
  for (int k = 0; k < 8; ++k)
#pragma unroll
    for (int q = 0; q < 4; ++q)
      pan[w][(k * 16 + lg * 4 + q) * 17 + lm] = acc[k][q];
  __syncthreads();

  if (tid < 256) {
    const int k = tid >> 5, rw = (tid >> 1) & 15, ch = tid & 1;
    const int boff = (k * 16 + rw) * 17 + ch * 8;
    f32x4 s0 = {0.f, 0.f, 0.f, 0.f}, s1 = {0.f, 0.f, 0.f, 0.f};
    for (int ss = 0; ss < 8; ++ss) {
      s0 += *(const f32x4*)&pan[ss][boff];
      s1 += *(const f32x4*)&pan[ss][boff + 4];
    }
    float v[8];
#pragma unroll
    for (int e = 0; e < 4; ++e) { v[e] = s0[e]; v[4 + e] = s1[e]; }
    const int n = rb * 16 + rw;

    if (seg <= 1) {
      u16* base = seg == 0 ? Vpk1 : Vpk2;
      const int blk = (seg == 0 ? p * 4 : p * 6) + (n >> 7);
      u16* d = base + ((size_t)blk << 15) + (size_t)k * 4096 +
               ((n >> 5) & 3) * 512 + ((n >> 3) & 3) * 128 + (n & 7);
      u16 ph[8], pl[8];
#pragma unroll
      for (int e = 0; e < 8; ++e) {
        const int m = p * 16 + ch * 8 + e;
        const float val = ((k == 0) && (n == m) ? 1.0f : 0.0f) - ALPHA_F * v[e];
        const u16 hh = bf_rnd(val);
        const u16 ll = bf_rnd(val - bf_val(hh));
        d[(size_t)(ch * 8 + e) * 8] = hh;
        d[2048 + (size_t)(ch * 8 + e) * 8] = ll;
        ph[e] = hh;
        pl[e] = ll;
      }
      // A-plane emission: operator entry [row n][col m] -> plane[k][m-chunk]
      if (seg == 0) {
        const size_t po = (((size_t)k * 64 + p * 2 + ch) * 512 + n) * 8;
        *(u16x8*)&V1pAh[po] = *(u16x8*)ph;
        *(u16x8*)&V1pAl[po] = *(u16x8*)pl;
      } else {
        const size_t po = (((size_t)k * 32 + p * 2 + ch) * 256 + n) * 8;
        *(u16x8*)&UpAh[po] = *(u16x8*)ph;
        *(u16x8*)&UpAl[po] = *(u16x8*)pl;
      }
    } else {
      const int b = n;
      float* cp_ = c1Z + (((size_t)k * 64 + p * 2 + ch) * 64 + b) * 8;
      u16x8 h8, l8;
#pragma unroll
      for (int e = 0; e < 8; ++e) {
        cp_[e] = v[e];
        const u16 hh = bf_rnd(v[e]);
        h8[e] = hh;
        l8[e] = bf_rnd(v[e] - bf_val(hh));
      }
      const size_t zo = (((size_t)k * 96 + 32 + p * 2 + ch) * 64 + b) * 8;
      *(u16x8*)&Z0h[zo] = h8;
      *(u16x8*)&Z0l[zo] = l8;
    }
  }
}

// ===========================================================================
// D3: compose2 — double-step operators.
//  seg0 (1024 blk): V1sq = V1~ ∘ V1~            -> V1sqI image (512x512)
//  seg1 ( 512 blk): M = B∘U + V1~∘B             -> Wcat2 rows 256..768
//  seg2 ( 256 blk): U2 = U∘U                    -> Wcat2 rows 0..256
// Same block structure as composeK; straight-value image pack.
// ===========================================================================
__global__ __launch_bounds__(512, 2) void compose2(
    const u16* __restrict__ V1pAh, const u16* __restrict__ V1pAl,
    const u16* __restrict__ UpAh, const u16* __restrict__ UpAl,
    const u16* __restrict__ BpAh, const u16* __restrict__ BpAl,
    const u16* __restrict__ Vpk1, const u16* __restrict__ Wcat,
    u16* V1sqI, u16* Wcat2) {
  __shared__ float pan[8][2176];

  const int bid = blockIdx.x, tid = threadIdx.x;
  const int w = tid >> 6, l = tid & 63;
  const int lg = l >> 4, lm = l & 15;

  int seg, rb, p;
  if (bid < 1024) { seg = 0; rb = bid & 31; p = bid >> 5; }
  else if (bid < 1536) { seg = 1; rb = (bid - 1024) & 31; p = (bid - 1024) >> 5; }
  else { seg = 2; rb = (bid - 1536) & 15; p = (bid - 1536) >> 4; }

  const int nwin = seg == 0 ? 2 : (seg == 1 ? 3 : 1);
  const int row = rb * 16 + lm;

  f32x4 acc[8];
#pragma unroll
  for (int k = 0; k < 8; ++k) acc[k] = f32x4{0.f, 0.f, 0.f, 0.f};

  for (int wi = 0; wi < nwin; ++wi) {
    const int g = w * nwin + wi;
    const u16 *Aph, *Apl;
    int AKC, AR, kcb;
    const u16* Vimg;
    if (seg == 0) {
      Aph = V1pAh; Apl = V1pAl; AKC = 64; AR = 512; kcb = g * 4;
      Vimg = Vpk1 + ((size_t)(p * 4 + (g >> 2)) << 15) + (g & 3) * 512;
    } else if (seg == 1) {
      if (g < 8) {  // M1 = B ∘ U  (K = 256 over U's row index)
        Aph = BpAh; Apl = BpAl; AKC = 32; AR = 512; kcb = g * 4;
        Vimg = Wcat + ((size_t)(p * 6 + (g >> 2)) << 15) + (g & 3) * 512;
      } else {      // M2 = V1~ ∘ B  (K = 512 over B's row index)
        const int g2_ = g - 8;
        Aph = V1pAh; Apl = V1pAl; AKC = 64; AR = 512; kcb = g2_ * 4;
        Vimg = Wcat + ((size_t)(p * 6 + 2 + (g2_ >> 2)) << 15) + (g2_ & 3) * 512;
      }
    } else {        // U2 = U ∘ U
      Aph = UpAh; Apl = UpAl; AKC = 32; AR = 256; kcb = g * 4;
      Vimg = Wcat + ((size_t)(p * 6 + (g >> 2)) << 15) + (g & 3) * 512;
    }
    Vimg += lg * 128 + lm * 8;
    const int kc = kcb + lg;
    bf16x8 ah[8], al[8];
#pragma unroll
    for (int a = 0; a < 8; ++a) {
      const size_t o = ((size_t)(a * AKC + kc) * AR + row) * 8;
      ah[a] = *(const bf16x8*)(Aph + o);
      al[a] = *(const bf16x8*)(Apl + o);
    }
    __builtin_amdgcn_s_setprio(1);
#pragma unroll
    for (int c = 0; c < 8; ++c) {
      const bf16x8 vhp = *(const bf16x8*)(Vimg + (size_t)c * 4096);
      const bf16x8 vlp = *(const bf16x8*)(Vimg + (size_t)c * 4096 + 2048);
      const bf16x8 vhn = negf(vhp), vln = negf(vlp);
#pragma unroll
      for (int a = 0; a < 8; ++a) {
        const int k = a ^ c;
        const bf16x8 vh = SGN(a, c) ? vhn : vhp;
        const bf16x8 vl = SGN(a, c) ? vln : vlp;
        acc[k] = mf(ah[a], vh, acc[k]);
        acc[k] = mf(al[a], vh, acc[k]);
        acc[k] = mf(ah[a], vl, acc[k]);
      }
    }
    __builtin_amdgcn_s_setprio(0);
  }

#pragma unroll
  for (int k = 0; k < 8; ++k)
#pragma unroll
    for (int q = 0; q < 4; ++q)
      pan[w][(k * 16 + lg * 4 + q) * 17 + lm] = acc[k][q];
  __syncthreads();

  if (tid < 256) {
    const int k = tid >> 5, rw = (tid >> 1) & 15, ch = tid & 1;
    const int boff = (k * 16 + rw) * 17 + ch * 8;
    f32x4 s0 = {0.f, 0.f, 0.f, 0.f}, s1 = {0.f, 0.f, 0.f, 0.f};
    for (int ss = 0; ss < 8; ++ss) {
      s0 += *(const f32x4*)&pan[ss][boff];
      s1 += *(const f32x4*)&pan[ss][boff + 4];
    }
    float v[8];
#pragma unroll
    for (int e = 0; e < 4; ++e) { v[e] = s0[e]; v[4 + e] = s1[e]; }
    const int n = rb * 16 + rw;

    u16* base = seg == 0 ? V1sqI : Wcat2;
    int blk;
    if (seg == 0) blk = p * 4 + (n >> 7);
    else if (seg == 1) blk = p * 6 + 2 + (n >> 7);
    else blk = p * 6 + (n >> 7);
    u16* d = base + ((size_t)blk << 15) + (size_t)k * 4096 +
             ((n >> 5) & 3) * 512 + ((n >> 3) & 3) * 128 + (n & 7);
#pragma unroll
    for (int e = 0; e < 8; ++e) {
      const float val = v[e];
      const u16 hh = bf_rnd(val);
      d[(size_t)(ch * 8 + e) * 8] = hh;
      d[2048 + (size_t)(ch * 8 + e) * 8] = bf_rnd(val - bf_val(hh));
    }
  }
}

// ===========================================================================
// Main-loop pair kernel (R11-validated structure). Parameterized operators,
// optional g2-add, optional fp32 add-format outputs (for constant capture).
// ===========================================================================
struct IArgs {
  const u16 *Zch, *Zcl;
  u16 *Znh, *Znl;
  const u16 *V1, *V2;
  const float *add1, *add2;
  float *oa1, *oa2;
  float *out1, *out2;
  int n_g1;
};

template <bool G1>
__device__ __forceinline__ void iter_body(const IArgs& A, int t18, int fin,
                                          float (*pan)[2176]) {
  const int bid = blockIdx.x, tid = threadIdx.x;
  const int w = tid >> 6, l = tid & 63;
  const int lg = l >> 4, lm = l & 15;
  const int rb = G1 ? bid : bid - A.n_g1;
  constexpr int NPAN = G1 ? 32 : 16;
  const int p = rb & (NPAN - 1);
  const int bh = rb / NPAN;
  const int b0 = bh * 16;
  constexpr int KW = G1 ? 64 : 96;
  constexpr int NW = G1 ? 2 : 3;
  constexpr int acb0 = G1 ? 32 : 0;
  constexpr int slmul = G1 ? 4 : 6;
  const u16* Vb = G1 ? A.V1 : A.V2;

  f32x4 acc[8];
#pragma unroll
  for (int k = 0; k < 8; ++k) acc[k] = f32x4{0.f, 0.f, 0.f, 0.f};

#pragma unroll
  for (int wi = 0; wi < NW; ++wi) {
    const int n0 = w * KW + wi * 32;
    const int sl = n0 >> 7, hst = (n0 >> 5) & 3;
    const u16* Vimg = Vb + ((size_t)(p * slmul + sl) << 15) + hst * 512 +
                      lg * 128 + lm * 8;
    const size_t ao = ((size_t)(acb0 + (n0 >> 3) + lg) * 64 + b0 + lm) * 8;
    bf16x8 ah[8], al[8];
#pragma unroll
    for (int a = 0; a < 8; ++a) {
      ah[a] = *(const bf16x8*)(A.Zch + (size_t)a * 49152 + ao);
      al[a] = *(const bf16x8*)(A.Zcl + (size_t)a * 49152 + ao);
    }
    __builtin_amdgcn_s_setprio(1);
#pragma unroll
    for (int c = 0; c < 8; ++c) {
      const bf16x8 vhp = *(const bf16x8*)(Vimg + (size_t)c * 4096);
      const bf16x8 vlp = *(const bf16x8*)(Vimg + (size_t)c * 4096 + 2048);
      const bf16x8 vhn = negf(vhp), vln = negf(vlp);
#pragma unroll
      for (int a = 0; a < 8; ++a) {
        const int k = a ^ c;
        const bf16x8 vh = SGN(a, c) ? vhn : vhp;
        const bf16x8 vl = SGN(a, c) ? vln : vlp;
        acc[k] = mf(ah[a], vh, acc[k]);
        acc[k] = mf(al[a], vh, acc[k]);
        acc[k] = mf(ah[a], vl, acc[k]);
      }
    }
    __builtin_amdgcn_s_setprio(0);
  }

#pragma unroll
  for (int k = 0; k < 8; ++k)
#pragma unroll
    for (int q = 0; q < 4; ++q)
      pan[w][(k * 16 + lg * 4 + q) * 17 + lm] = acc[k][q];
  __syncthreads();

  if (tid < 256) {
    const int k = tid >> 5, row = (tid >> 1) & 15, ch = tid & 1;
    const int boff = (k * 16 + row) * 17 + ch * 8;
    f32x4 s0 = {0.f, 0.f, 0.f, 0.f}, s1 = {0.f, 0.f, 0.f, 0.f};
    for (int ss = 0; ss < 8; ++ss) {
      s0 += *(const f32x4*)&pan[ss][boff];
      s1 += *(const f32x4*)&pan[ss][boff + 4];
    }
    const int b = b0 + row;
    if constexpr (G1) {
      if (A.add1) {
        const float* ca = A.add1 + (((size_t)k * 64 + p * 2 + ch) * 64 + b) * 8;
        s0 += *(const f32x4*)ca;
        s1 += *(const f32x4*)(ca + 4);
      }
    } else {
      if (A.add2) {
        const float* ca = A.add2 + (((size_t)k * 32 + p * 2 + ch) * 64 + b) * 8;
        s0 += *(const f32x4*)ca;
        s1 += *(const f32x4*)(ca + 4);
      }
    }
    float v[8];
#pragma unroll
    for (int e = 0; e < 4; ++e) { v[e] = s0[e]; v[4 + e] = s1[e]; }
    if constexpr (G1) {
      if (A.oa1) {
        float* q = A.oa1 + (((size_t)k * 64 + p * 2 + ch) * 64 + b) * 8;
#pragma unroll
        for (int e = 0; e < 8; ++e) q[e] = v[e];
      }
    } else {
      if (A.oa2) {
        float* q = A.oa2 + (((size_t)k * 32 + p * 2 + ch) * 64 + b) * 8;
#pragma unroll
        for (int e = 0; e < 8; ++e) q[e] = v[e];
      }
    }
    if (!fin) {
      u16x8 h8, l8;
#pragma unroll
      for (int e = 0; e < 8; ++e) {
        const u16 hh = bf_rnd(v[e]);
        h8[e] = hh;
        l8[e] = bf_rnd(v[e] - bf_val(hh));
      }
      const size_t zo =
          (((size_t)k * 96 + (G1 ? 32 : 0) + p * 2 + ch) * 64 + b) * 8;
      *(u16x8*)&A.Znh[zo] = h8;
      *(u16x8*)&A.Znl[zo] = l8;
    }
    if constexpr (G1) {
      if (t18) {
#pragma unroll
        for (int e = 0; e < 8; ++e)
          A.out1[((size_t)b * 512 + p * 16 + ch * 8 + e) * 8 + k] = v[e];
      }
    } else {
      if (fin) {
#pragma unroll
        for (int e = 0; e < 8; ++e)
          A.out2[((size_t)b * 256 + p * 16 + ch * 8 + e) * 8 + k] = v[e];
      }
    }
  }
}

__global__ __launch_bounds__(512, 2) void iter_k(IArgs A, int t18, int fin) {
  __shared__ float pan[8][2176];
  if ((int)blockIdx.x < A.n_g1) iter_body<true>(A, t18, fin, pan);
  else iter_body<false>(A, t18, fin, pan);
}

extern "C" void kernel_launch(void* const* d_in, const int* in_sizes, int n_in,
                              void* d_out, int out_size, void* d_ws,
                              size_t ws_size, hipStream_t stream) {
  const float* x = (const float*)d_in[0];
  const float* w1 = (const float*)d_in[1];
  const float* w2 = (const float*)d_in[2];

  float* out0 = (float*)d_out;
  float* out1 = out0 + 131072;
  float* out2 = out1 + 262144;

  char* W = (char*)d_ws;
  const size_t MB = 1ull << 20;
  u16* Vpk1 = (u16*)(W);                    // 8 MB
  u16* Wcat = (u16*)(W + 8 * MB);           // 6 MB
  u16* Q1 = (u16*)(W + 14 * MB);            // 4
  u16* Q2 = (u16*)(W + 18 * MB);            // 4
  u16* Qc1 = (u16*)(W + 22 * MB);           // 4
  u16* P1h = (u16*)(W + 26 * MB);
  u16* P1l = (u16*)(W + 28 * MB);
  u16* P2h = (u16*)(W + 30 * MB);
  u16* P2l = (u16*)(W + 32 * MB);
  u16* Axh = (u16*)(W + 34 * MB);
  u16* Axl = (u16*)(W + 34 * MB + 262144);
  float* c1Z = (float*)(W + 35 * MB);       // 1 MB
  u16* V1sqI = (u16*)(W + 36 * MB);         // 8 MB
  u16* Wcat2 = (u16*)(W + 44 * MB);         // 6 MB
  u16* V1pAh = (u16*)(W + 50 * MB);         // 4 MB
  u16* V1pAl = (u16*)(W + 54 * MB);         // 4 MB
  u16* UpAh = (u16*)(W + 58 * MB);          // 1 MB
  u16* UpAl = (u16*)(W + 59 * MB);          // 1 MB
  u16* BpAh = (u16*)(W + 60 * MB);          // 2 MB
  u16* BpAl = (u16*)(W + 62 * MB);          // 2 MB
  float* c1bZ = (float*)(W + 64 * MB);      // 1 MB
  float* d2Z = (float*)(W + 65 * MB);       // 0.5 MB
  u16* Z0h = (u16*)(W + 66 * MB);           // 768 KB each
  u16* Z0l = Z0h + 393216;
  u16* Z1h = Z0h + 786432;
  u16* Z1l = Z0h + 1179648;

  // D1: pack raw inputs (+ B planes)
  pack_in<<<2368, 256, 0, stream>>>(x, w1, w2, P1h, P1l, Q1, Qc1, P2h, P2l, Q2,
                                    Axh, Axl, Wcat, BpAh, BpAl, Z0h, Z0l, out0);

  // D2: compose single-step operators (+ operator A-planes)
  composeK<<<1408, 512, 0, stream>>>(P1h, P1l, Q1, P2h, P2l, Q2, Axh, Axl, Qc1,
                                     Vpk1, Wcat, V1pAh, V1pAl, UpAh, UpAl,
                                     Z0h, Z0l, c1Z);

  // D3: compose double-step operators
  compose2<<<1792, 512, 0, stream>>>(V1pAh, V1pAl, UpAh, UpAl, BpAh, BpAl,
                                     Vpk1, Wcat, V1sqI, Wcat2);

  // D4: seed step (Z0 -> Z1 = (S2_1, S1_2)) + capture constants d2=S2_1,
  //     c1b=S1_2 in fp32 add-layout
  {
    IArgs ia{Z0h, Z0l, Z1h, Z1l, Vpk1, Wcat, c1Z, nullptr,
             c1bZ, d2Z, out1, out2, 128};
    iter_k<<<192, 512, 0, stream>>>(ia, 0, 0);
  }

  // D5..D13: 9 fused double-steps: (S2_t, S1_{t+1}) -> (S2_{t+2}, S1_{t+3})
  for (int tau = 0; tau < 9; ++tau) {
    const bool odd = tau & 1;
    IArgs ia{odd ? Z0h : Z1h, odd ? Z0l : Z1l,
             odd ? Z1h : Z0h, odd ? Z1l : Z0l,
             V1sqI, Wcat2, c1bZ, d2Z, nullptr, nullptr, out1, out2, 128};
    iter_k<<<192, 512, 0, stream>>>(ia, tau == 8 ? 1 : 0, 0);
  }

  // D14: final single g2 step: S2_20 = [S2_19 | S1_20] * Wcat -> out2
  {
    IArgs ia{Z0h, Z0l, Z1h, Z1l, Vpk1, Wcat, nullptr, nullptr,
             nullptr, nullptr, out1, out2, 0};
    iter_k<<<64, 512, 0, stream>>>(ia, 0, 1);
  }
}

// Round 15
// 354.581 us; speedup vs baseline: 1.2953x; 1.0238x over previous
//
#include <hip/hip_runtime.h>

typedef unsigned short u16;
typedef __attribute__((ext_vector_type(4))) float f32x4;
typedef __attribute__((ext_vector_type(8))) __bf16 bf16x8;
typedef __attribute__((ext_vector_type(8))) u16 u16x8;

#define ALPHA_F 0.1f

// Cl(3,0): e_a * e_c = (-1)^p e_{a^c}  [validated R1-R14]
__device__ __host__ constexpr bool SGN(int a, int c) {
  return ((((c & 1) & (((a >> 1) ^ (a >> 2)) & 1)) ^
           (((c >> 1) & 1) & ((a >> 2) & 1))) != 0);
}
__device__ __host__ constexpr float REVF(int c) {
  const int r = (c & 1) + ((c >> 1) & 1) + ((c >> 2) & 1);
  return (r >= 2) ? -1.f : 1.f;
}
__device__ __forceinline__ u16 bf_rnd(float f) {
  unsigned u = __float_as_uint(f);
  return (u16)((u + 0x7FFFu + ((u >> 16) & 1u)) >> 16);
}
__device__ __forceinline__ float bf_val(u16 h) {
  return __uint_as_float(((unsigned)h) << 16);
}
__device__ __forceinline__ f32x4 mf(bf16x8 a, bf16x8 b, f32x4 c) {
  return __builtin_amdgcn_mfma_f32_16x16x32_bf16(a, b, c, 0, 0, 0);
}
__device__ __forceinline__ bf16x8 negf(bf16x8 v) {
  u16x8 u = __builtin_bit_cast(u16x8, v);
  const u16x8 m = {0x8000, 0x8000, 0x8000, 0x8000, 0x8000, 0x8000, 0x8000, 0x8000};
  u = u ^ m;
  return __builtin_bit_cast(bf16x8, u);
}

// ===========================================================================
// D1: pack raw inputs (validated R13/R14). UNCHANGED.
// ===========================================================================
__global__ __launch_bounds__(256) void pack_in(
    const float* __restrict__ x, const float* __restrict__ w1,
    const float* __restrict__ w2, u16* P1h, u16* P1l, u16* Q1, u16* Qc1,
    u16* P2h, u16* P2l, u16* Q2, u16* Axh, u16* Axl, u16* Vpk2,
    u16* BpAh, u16* BpAl, u16* Z0h, u16* Z0l, float* out0) {
  const int t = blockIdx.x * 256 + threadIdx.x;
  if (t < 131072) {
    const int r = t >> 9, cc = t & 511;
    const float* s = w1 + ((size_t)r * 512 + cc) * 8;
    float v[8];
#pragma unroll
    for (int c = 0; c < 8; ++c) v[c] = s[c];
    const size_t qo = (size_t)((cc >> 4) * 2 + (r >> 7)) * 32768 +
                      ((r >> 5) & 3) * 512 + ((r >> 3) & 3) * 128 +
                      (cc & 15) * 8 + (r & 7);
#pragma unroll
    for (int c = 0; c < 8; ++c) {
      const float q1 = REVF(c) * v[c];
      u16 h = bf_rnd(q1);
      Q1[qo + c * 4096] = h;
      Q1[qo + c * 4096 + 2048] = bf_rnd(q1 - bf_val(h));
      const float qc = ALPHA_F * q1;
      h = bf_rnd(qc);
      Qc1[qo + c * 4096] = h;
      Qc1[qo + c * 4096 + 2048] = bf_rnd(qc - bf_val(h));
    }
  } else if (t < 262144) {
    const int u = t - 131072;
    const int r = u >> 8, c2 = u & 255;
    const float* s = w2 + ((size_t)r * 256 + c2) * 8;
    float v[8];
#pragma unroll
    for (int c = 0; c < 8; ++c) v[c] = s[c];
    const size_t tail = ((r >> 5) & 3) * 512 + ((r >> 3) & 3) * 128 +
                        (c2 & 15) * 8 + (r & 7);
    const size_t qo = (size_t)((c2 >> 4) * 4 + (r >> 7)) * 32768 + tail;
    const size_t wo = (size_t)((c2 >> 4) * 6 + 2 + (r >> 7)) * 32768 + tail;
#pragma unroll
    for (int c = 0; c < 8; ++c) {
      const float q2 = REVF(c) * v[c];
      u16 h = bf_rnd(q2);
      Q2[qo + c * 4096] = h;
      Q2[qo + c * 4096 + 2048] = bf_rnd(q2 - bf_val(h));
      const float qw = ALPHA_F * q2;
      h = bf_rnd(qw);
      const u16 lo = bf_rnd(qw - bf_val(h));
      Vpk2[wo + c * 4096] = h;
      Vpk2[wo + c * 4096 + 2048] = lo;
      const size_t bo = ((size_t)(c * 32 + (c2 >> 3)) * 512 + r) * 8 + (c2 & 7);
      BpAh[bo] = h;
      BpAl[bo] = lo;
    }
  } else if (t < 393216) {
    const int u = t - 262144;
    const int r = u & 255, cc = u >> 8;
    const float* s = w1 + ((size_t)r * 512 + cc) * 8;
#pragma unroll
    for (int a = 0; a < 8; ++a) {
      const float v = s[a];
      const u16 h = bf_rnd(v);
      const size_t o = ((size_t)(a * 32 + (r >> 3)) * 512 + cc) * 8 + (r & 7);
      P1h[o] = h;
      P1l[o] = bf_rnd(v - bf_val(h));
    }
  } else if (t < 524288) {
    const int u = t - 393216;
    const int r = u & 511, c2 = u >> 9;
    const float* s = w2 + ((size_t)r * 256 + c2) * 8;
#pragma unroll
    for (int a = 0; a < 8; ++a) {
      const float v = s[a];
      const u16 h = bf_rnd(v);
      const size_t o = ((size_t)(a * 64 + (r >> 3)) * 256 + c2) * 8 + (r & 7);
      P2h[o] = h;
      P2l[o] = bf_rnd(v - bf_val(h));
    }
  } else if (t < 540672) {
    const int u = t - 524288;
    const int b = u >> 8, n = u & 255;
    const float* s = x + ((size_t)b * 256 + n) * 8;
#pragma unroll
    for (int a = 0; a < 8; ++a) {
      const u16 h = bf_rnd(s[a]);
      const size_t o = ((size_t)(a * 32 + (n >> 3)) * 64 + b) * 8 + (n & 7);
      Axh[o] = h;
      Axl[o] = bf_rnd(s[a] - bf_val(h));
    }
  } else if (t < 573440) {
    const int u = t - 540672;
    ((float4*)out0)[u] = ((const float4*)x)[u];
  } else if (t < 606208) {
    const int u = t - 573440;
    const int hl = u >> 14, i = u & 16383;
    const int a = i >> 11, j = i & 2047;
    const u16x8 z = {0, 0, 0, 0, 0, 0, 0, 0};
    u16* Z = hl ? Z0l : Z0h;
    *(u16x8*)&Z[(size_t)a * 49152 + (size_t)j * 8] = z;
  }
}

// ===========================================================================
// D2: composeK (validated R14). UNCHANGED.
// ===========================================================================
__global__ __launch_bounds__(512, 2) void composeK(
    const u16* __restrict__ P1h, const u16* __restrict__ P1l,
    const u16* __restrict__ Q1, const u16* __restrict__ P2h,
    const u16* __restrict__ P2l, const u16* __restrict__ Q2,
    const u16* __restrict__ Axh, const u16* __restrict__ Axl,
    const u16* __restrict__ Qc1, u16* Vpk1, u16* Vpk2,
    u16* V1pAh, u16* V1pAl, u16* UpAh, u16* UpAl,
    u16* Z0h, u16* Z0l, float* c1Z) {
  __shared__ float pan[8][2176];

  const int bid = blockIdx.x, tid = threadIdx.x;
  const int w = tid >> 6, l = tid & 63;
  const int lg = l >> 4, lm = l & 15;

  int seg, rb, p;
  if (bid < 256) { seg = 1; rb = bid & 15; p = bid >> 4; }
  else if (bid < 1280) { seg = 0; rb = (bid - 256) & 31; p = (bid - 256) >> 5; }
  else { seg = 2; rb = (bid - 1280) & 3; p = (bid - 1280) >> 2; }

  const u16* Ah_ = seg == 0 ? P1h : (seg == 1 ? P2h : Axh);
  const u16* Al_ = seg == 0 ? P1l : (seg == 1 ? P2l : Axl);
  const u16* Vb = seg == 0 ? Q1 : (seg == 1 ? Q2 : Qc1);
  const int NROW = seg == 0 ? 512 : (seg == 1 ? 256 : 64);
  const int KC = seg == 1 ? 64 : 32;
  const int NW = seg == 1 ? 2 : 1;
  const int slmul = seg == 1 ? 4 : 2;
  const int row = rb * 16 + lm;

  f32x4 acc[8];
#pragma unroll
  for (int k = 0; k < 8; ++k) acc[k] = f32x4{0.f, 0.f, 0.f, 0.f};

  for (int wi = 0; wi < NW; ++wi) {
    const int n0 = w * (NW * 32) + wi * 32;
    const int sl = n0 >> 7, hst = (n0 >> 5) & 3;
    const u16* Vimg =
        Vb + ((size_t)(p * slmul + sl) << 15) + hst * 512 + lg * 128 + lm * 8;
    const int kc = (n0 >> 3) + lg;
    bf16x8 ah[8], al[8];
#pragma unroll
    for (int a = 0; a < 8; ++a) {
      const size_t o = ((size_t)(a * KC + kc) * NROW + row) * 8;
      ah[a] = *(const bf16x8*)(Ah_ + o);
      al[a] = *(const bf16x8*)(Al_ + o);
    }
    __builtin_amdgcn_s_setprio(1);
#pragma unroll
    for (int c = 0; c < 8; ++c) {
      const bf16x8 vhp = *(const bf16x8*)(Vimg + (size_t)c * 4096);
      const bf16x8 vlp = *(const bf16x8*)(Vimg + (size_t)c * 4096 + 2048);
      const bf16x8 vhn = negf(vhp), vln = negf(vlp);
#pragma unroll
      for (int a = 0; a < 8; ++a) {
        const int k = a ^ c;
        const bf16x8 vh = SGN(a, c) ? vhn : vhp;
        const bf16x8 vl = SGN(a, c) ? vln : vlp;
        acc[k] = mf(ah[a], vh, acc[k]);
        acc[k] = mf(al[a], vh, acc[k]);
        acc[k] = mf(ah[a], vl, acc[k]);
      }
    }
    __builtin_amdgcn_s_setprio(0);
  }

#pragma unroll
  for (int k = 0; k < 8; ++k)
#pragma unroll
    for (int q = 0; q < 4; ++q)
      pan[w][(k * 16 + lg * 4 + q) * 17 + lm] = acc[k][q];
  __syncthreads();

  if (tid < 256) {
    const int k = tid >> 5, rw = (tid >> 1) & 15, ch = tid & 1;
    const int boff = (k * 16 + rw) * 17 + ch * 8;
    f32x4 s0 = {0.f, 0.f, 0.f, 0.f}, s1 = {0.f, 0.f, 0.f, 0.f};
    for (int ss = 0; ss < 8; ++ss) {
      s0 += *(const f32x4*)&pan[ss][boff];
      s1 += *(const f32x4*)&pan[ss][boff + 4];
    }
    float v[8];
#pragma unroll
    for (int e = 0; e < 4; ++e) { v[e] = s0[e]; v[4 + e] = s1[e]; }
    const int n = rb * 16 + rw;

    if (seg <= 1) {
      u16* base = seg == 0 ? Vpk1 : Vpk2;
      const int blk = (seg == 0 ? p * 4 : p * 6) + (n >> 7);
      u16* d = base + ((size_t)blk << 15) + (size_t)k * 4096 +
               ((n >> 5) & 3) * 512 + ((n >> 3) & 3) * 128 + (n & 7);
      u16 ph[8], pl[8];
#pragma unroll
      for (int e = 0; e < 8; ++e) {
        const int m = p * 16 + ch * 8 + e;
        const float val = ((k == 0) && (n == m) ? 1.0f : 0.0f) - ALPHA_F * v[e];
        const u16 hh = bf_rnd(val);
        const u16 ll = bf_rnd(val - bf_val(hh));
        d[(size_t)(ch * 8 + e) * 8] = hh;
        d[2048 + (size_t)(ch * 8 + e) * 8] = ll;
        ph[e] = hh;
        pl[e] = ll;
      }
      if (seg == 0) {
        const size_t po = (((size_t)k * 64 + p * 2 + ch) * 512 + n) * 8;
        *(u16x8*)&V1pAh[po] = *(u16x8*)ph;
        *(u16x8*)&V1pAl[po] = *(u16x8*)pl;
      } else {
        const size_t po = (((size_t)k * 32 + p * 2 + ch) * 256 + n) * 8;
        *(u16x8*)&UpAh[po] = *(u16x8*)ph;
        *(u16x8*)&UpAl[po] = *(u16x8*)pl;
      }
    } else {
      const int b = n;
      float* cp_ = c1Z + (((size_t)k * 64 + p * 2 + ch) * 64 + b) * 8;
      u16x8 h8, l8;
#pragma unroll
      for (int e = 0; e < 8; ++e) {
        cp_[e] = v[e];
        const u16 hh = bf_rnd(v[e]);
        h8[e] = hh;
        l8[e] = bf_rnd(v[e] - bf_val(hh));
      }
      const size_t zo = (((size_t)k * 96 + 32 + p * 2 + ch) * 64 + b) * 8;
      *(u16x8*)&Z0h[zo] = h8;
      *(u16x8*)&Z0l[zo] = l8;
    }
  }
}

// ===========================================================================
// Main-loop iter body (R14-validated); vbid param so it can be embedded.
// ===========================================================================
struct IArgs {
  const u16 *Zch, *Zcl;
  u16 *Znh, *Znl;
  const u16 *V1, *V2;
  const float *add1, *add2;
  float *oa1, *oa2;
  float *out1, *out2;
  int n_g1;
};

template <bool G1>
__device__ __forceinline__ void iter_body(const IArgs& A, int vbid, int t18,
                                          int fin, float (*pan)[2176]) {
  const int tid = threadIdx.x;
  const int w = tid >> 6, l = tid & 63;
  const int lg = l >> 4, lm = l & 15;
  const int rb = G1 ? vbid : vbid - A.n_g1;
  constexpr int NPAN = G1 ? 32 : 16;
  const int p = rb & (NPAN - 1);
  const int bh = rb / NPAN;
  const int b0 = bh * 16;
  constexpr int KW = G1 ? 64 : 96;
  constexpr int NW = G1 ? 2 : 3;
  constexpr int acb0 = G1 ? 32 : 0;
  constexpr int slmul = G1 ? 4 : 6;
  const u16* Vb = G1 ? A.V1 : A.V2;

  f32x4 acc[8];
#pragma unroll
  for (int k = 0; k < 8; ++k) acc[k] = f32x4{0.f, 0.f, 0.f, 0.f};

#pragma unroll
  for (int wi = 0; wi < NW; ++wi) {
    const int n0 = w * KW + wi * 32;
    const int sl = n0 >> 7, hst = (n0 >> 5) & 3;
    const u16* Vimg = Vb + ((size_t)(p * slmul + sl) << 15) + hst * 512 +
                      lg * 128 + lm * 8;
    const size_t ao = ((size_t)(acb0 + (n0 >> 3) + lg) * 64 + b0 + lm) * 8;
    bf16x8 ah[8], al[8];
#pragma unroll
    for (int a = 0; a < 8; ++a) {
      ah[a] = *(const bf16x8*)(A.Zch + (size_t)a * 49152 + ao);
      al[a] = *(const bf16x8*)(A.Zcl + (size_t)a * 49152 + ao);
    }
    __builtin_amdgcn_s_setprio(1);
#pragma unroll
    for (int c = 0; c < 8; ++c) {
      const bf16x8 vhp = *(const bf16x8*)(Vimg + (size_t)c * 4096);
      const bf16x8 vlp = *(const bf16x8*)(Vimg + (size_t)c * 4096 + 2048);
      const bf16x8 vhn = negf(vhp), vln = negf(vlp);
#pragma unroll
      for (int a = 0; a < 8; ++a) {
        const int k = a ^ c;
        const bf16x8 vh = SGN(a, c) ? vhn : vhp;
        const bf16x8 vl = SGN(a, c) ? vln : vlp;
        acc[k] = mf(ah[a], vh, acc[k]);
        acc[k] = mf(al[a], vh, acc[k]);
        acc[k] = mf(ah[a], vl, acc[k]);
      }
    }
    __builtin_amdgcn_s_setprio(0);
  }

#pragma unroll
  for (int k = 0; k < 8; ++k)
#pragma unroll
    for (int q = 0; q < 4; ++q)
      pan[w][(k * 16 + lg * 4 + q) * 17 + lm] = acc[k][q];
  __syncthreads();

  if (tid < 256) {
    const int k = tid >> 5, row = (tid >> 1) & 15, ch = tid & 1;
    const int boff = (k * 16 + row) * 17 + ch * 8;
    f32x4 s0 = {0.f, 0.f, 0.f, 0.f}, s1 = {0.f, 0.f, 0.f, 0.f};
    for (int ss = 0; ss < 8; ++ss) {
      s0 += *(const f32x4*)&pan[ss][boff];
      s1 += *(const f32x4*)&pan[ss][boff + 4];
    }
    const int b = b0 + row;
    if constexpr (G1) {
      if (A.add1) {
        const float* ca = A.add1 + (((size_t)k * 64 + p * 2 + ch) * 64 + b) * 8;
        s0 += *(const f32x4*)ca;
        s1 += *(const f32x4*)(ca + 4);
      }
    } else {
      if (A.add2) {
        const float* ca = A.add2 + (((size_t)k * 32 + p * 2 + ch) * 64 + b) * 8;
        s0 += *(const f32x4*)ca;
        s1 += *(const f32x4*)(ca + 4);
      }
    }
    float v[8];
#pragma unroll
    for (int e = 0; e < 4; ++e) { v[e] = s0[e]; v[4 + e] = s1[e]; }
    if constexpr (G1) {
      if (A.oa1) {
        float* q = A.oa1 + (((size_t)k * 64 + p * 2 + ch) * 64 + b) * 8;
#pragma unroll
        for (int e = 0; e < 8; ++e) q[e] = v[e];
      }
    } else {
      if (A.oa2) {
        float* q = A.oa2 + (((size_t)k * 32 + p * 2 + ch) * 64 + b) * 8;
#pragma unroll
        for (int e = 0; e < 8; ++e) q[e] = v[e];
      }
    }
    if (!fin) {
      u16x8 h8, l8;
#pragma unroll
      for (int e = 0; e < 8; ++e) {
        const u16 hh = bf_rnd(v[e]);
        h8[e] = hh;
        l8[e] = bf_rnd(v[e] - bf_val(hh));
      }
      const size_t zo =
          (((size_t)k * 96 + (G1 ? 32 : 0) + p * 2 + ch) * 64 + b) * 8;
      *(u16x8*)&A.Znh[zo] = h8;
      *(u16x8*)&A.Znl[zo] = l8;
    }
    if constexpr (G1) {
      if (t18) {
#pragma unroll
        for (int e = 0; e < 8; ++e)
          A.out1[((size_t)b * 512 + p * 16 + ch * 8 + e) * 8 + k] = v[e];
      }
    } else {
      if (fin) {
#pragma unroll
        for (int e = 0; e < 8; ++e)
          A.out2[((size_t)b * 256 + p * 16 + ch * 8 + e) * 8 + k] = v[e];
      }
    }
  }
}

__global__ __launch_bounds__(512, 2) void iter_k(IArgs A, int t18, int fin) {
  __shared__ float pan[8][2176];
  if ((int)blockIdx.x < A.n_g1) iter_body<true>(A, blockIdx.x, t18, fin, pan);
  else iter_body<false>(A, blockIdx.x, t18, fin, pan);
}

// ===========================================================================
// D3: combo = seed step (blocks 0..191, independent) + compose2:
//   seg0 (512 blk, 32-ROW TILES): V1sq = V1~ ∘ V1~ -> V1sqI
//   seg1 (512 blk): M = B∘U + V1~∘B -> Wcat2 rows 256..768
//   seg2 (256 blk): U2 = U∘U        -> Wcat2 rows 0..256
// Per-output arithmetic identical to R14 compose2.
// ===========================================================================
struct C2A {
  const u16 *V1pAh, *V1pAl, *UpAh, *UpAl, *BpAh, *BpAl;
  const u16 *Vpk1, *Wcat;
  u16 *V1sqI, *Wcat2;
};

__global__ __launch_bounds__(512) void combo(IArgs S, C2A C) {
  __shared__ float pan[8][2176];
  const int bid = blockIdx.x, tid = threadIdx.x;

  if (bid < 192) {  // seed step
    if (bid < S.n_g1) iter_body<true>(S, bid, 0, 0, pan);
    else iter_body<false>(S, bid, 0, 0, pan);
    return;
  }
  const int cb = bid - 192;
  const int w = tid >> 6, l = tid & 63;
  const int lg = l >> 4, lm = l & 15;

  if (cb < 512) {
    // ---- seg0 v2: 32-row tiles ----
    const int p = cb >> 4, rq = cb & 15;
    const int row0 = rq * 32 + lm, row1 = row0 + 16;
    f32x4 acc0[8], acc1[8];
#pragma unroll
    for (int k = 0; k < 8; ++k) {
      acc0[k] = f32x4{0.f, 0.f, 0.f, 0.f};
      acc1[k] = f32x4{0.f, 0.f, 0.f, 0.f};
    }
#pragma unroll
    for (int wi = 0; wi < 2; ++wi) {
      const int g = w * 2 + wi;
      const u16* Vimg = C.Vpk1 + ((size_t)(p * 4 + (g >> 2)) << 15) +
                        (g & 3) * 512 + lg * 128 + lm * 8;
      const int kc = g * 4 + lg;
      bf16x8 a0h[8], a0l[8], a1h[8], a1l[8];
#pragma unroll
      for (int a = 0; a < 8; ++a) {
        const size_t o0 = ((size_t)(a * 64 + kc) * 512 + row0) * 8;
        const size_t o1 = ((size_t)(a * 64 + kc) * 512 + row1) * 8;
        a0h[a] = *(const bf16x8*)(C.V1pAh + o0);
        a0l[a] = *(const bf16x8*)(C.V1pAl + o0);
        a1h[a] = *(const bf16x8*)(C.V1pAh + o1);
        a1l[a] = *(const bf16x8*)(C.V1pAl + o1);
      }
      __builtin_amdgcn_s_setprio(1);
#pragma unroll
      for (int c = 0; c < 8; ++c) {
        const bf16x8 vhp = *(const bf16x8*)(Vimg + (size_t)c * 4096);
        const bf16x8 vlp = *(const bf16x8*)(Vimg + (size_t)c * 4096 + 2048);
        const bf16x8 vhn = negf(vhp), vln = negf(vlp);
#pragma unroll
        for (int a = 0; a < 8; ++a) {
          const int k = a ^ c;
          const bf16x8 vh = SGN(a, c) ? vhn : vhp;
          const bf16x8 vl = SGN(a, c) ? vln : vlp;
          acc0[k] = mf(a0h[a], vh, acc0[k]);
          acc0[k] = mf(a0l[a], vh, acc0[k]);
          acc0[k] = mf(a0h[a], vl, acc0[k]);
          acc1[k] = mf(a1h[a], vh, acc1[k]);
          acc1[k] = mf(a1l[a], vh, acc1[k]);
          acc1[k] = mf(a1h[a], vl, acc1[k]);
        }
      }
      __builtin_amdgcn_s_setprio(0);
    }
#pragma unroll
    for (int rg = 0; rg < 2; ++rg) {
#pragma unroll
      for (int k = 0; k < 8; ++k)
#pragma unroll
        for (int q = 0; q < 4; ++q)
          pan[w][(k * 16 + lg * 4 + q) * 17 + lm] =
              rg ? acc1[k][q] : acc0[k][q];
      __syncthreads();
      if (tid < 256) {
        const int k = tid >> 5, rw = (tid >> 1) & 15, ch = tid & 1;
        const int boff = (k * 16 + rw) * 17 + ch * 8;
        f32x4 s0 = {0.f, 0.f, 0.f, 0.f}, s1 = {0.f, 0.f, 0.f, 0.f};
        for (int ss = 0; ss < 8; ++ss) {
          s0 += *(const f32x4*)&pan[ss][boff];
          s1 += *(const f32x4*)&pan[ss][boff + 4];
        }
        float v[8];
#pragma unroll
        for (int e = 0; e < 4; ++e) { v[e] = s0[e]; v[4 + e] = s1[e]; }
        const int n = rq * 32 + rg * 16 + rw;
        const int blk = p * 4 + (n >> 7);
        u16* d = C.V1sqI + ((size_t)blk << 15) + (size_t)k * 4096 +
                 ((n >> 5) & 3) * 512 + ((n >> 3) & 3) * 128 + (n & 7);
#pragma unroll
        for (int e = 0; e < 8; ++e) {
          const float val = v[e];
          const u16 hh = bf_rnd(val);
          d[(size_t)(ch * 8 + e) * 8] = hh;
          d[2048 + (size_t)(ch * 8 + e) * 8] = bf_rnd(val - bf_val(hh));
        }
      }
      __syncthreads();
    }
    return;
  }

  // ---- seg1 / seg2 (R14 logic, reindexed) ----
  int seg, rb, p;
  if (cb < 1024) { seg = 1; rb = (cb - 512) & 31; p = (cb - 512) >> 5; }
  else { seg = 2; rb = (cb - 1024) & 15; p = (cb - 1024) >> 4; }
  const int nwin = seg == 1 ? 3 : 1;
  const int row = rb * 16 + lm;

  f32x4 acc[8];
#pragma unroll
  for (int k = 0; k < 8; ++k) acc[k] = f32x4{0.f, 0.f, 0.f, 0.f};

  for (int wi = 0; wi < nwin; ++wi) {
    const int g = w * nwin + wi;
    const u16 *Aph, *Apl;
    int AKC, AR, kcb;
    const u16* Vimg;
    if (seg == 1) {
      if (g < 8) {  // M1 = B ∘ U
        Aph = C.BpAh; Apl = C.BpAl; AKC = 32; AR = 512; kcb = g * 4;
        Vimg = C.Wcat + ((size_t)(p * 6 + (g >> 2)) << 15) + (g & 3) * 512;
      } else {      // M2 = V1~ ∘ B
        const int g2_ = g - 8;
        Aph = C.V1pAh; Apl = C.V1pAl; AKC = 64; AR = 512; kcb = g2_ * 4;
        Vimg = C.Wcat + ((size_t)(p * 6 + 2 + (g2_ >> 2)) << 15) + (g2_ & 3) * 512;
      }
    } else {        // U2 = U ∘ U
      Aph = C.UpAh; Apl = C.UpAl; AKC = 32; AR = 256; kcb = g * 4;
      Vimg = C.Wcat + ((size_t)(p * 6 + (g >> 2)) << 15) + (g & 3) * 512;
    }
    Vimg += lg * 128 + lm * 8;
    const int kc = kcb + lg;
    bf16x8 ah[8], al[8];
#pragma unroll
    for (int a = 0; a < 8; ++a) {
      const size_t o = ((size_t)(a * AKC + kc) * AR + row) * 8;
      ah[a] = *(const bf16x8*)(Aph + o);
      al[a] = *(const bf16x8*)(Apl + o);
    }
    __builtin_amdgcn_s_setprio(1);
#pragma unroll
    for (int c = 0; c < 8; ++c) {
      const bf16x8 vhp = *(const bf16x8*)(Vimg + (size_t)c * 4096);
      const bf16x8 vlp = *(const bf16x8*)(Vimg + (size_t)c * 4096 + 2048);
      const bf16x8 vhn = negf(vhp), vln = negf(vlp);
#pragma unroll
      for (int a = 0; a < 8; ++a) {
        const int k = a ^ c;
        const bf16x8 vh = SGN(a, c) ? vhn : vhp;
        const bf16x8 vl = SGN(a, c) ? vln : vlp;
        acc[k] = mf(ah[a], vh, acc[k]);
        acc[k] = mf(al[a], vh, acc[k]);
        acc[k] = mf(ah[a], vl, acc[k]);
      }
    }
    __builtin_amdgcn_s_setprio(0);
  }

#pragma unroll
  for (int k = 0; k < 8; ++k)
#pragma unroll
    for (int q = 0; q < 4; ++q)
      pan[w][(k * 16 + lg * 4 + q) * 17 + lm] = acc[k][q];
  __syncthreads();

  if (tid < 256) {
    const int k = tid >> 5, rw = (tid >> 1) & 15, ch = tid & 1;
    const int boff = (k * 16 + rw) * 17 + ch * 8;
    f32x4 s0 = {0.f, 0.f, 0.f, 0.f}, s1 = {0.f, 0.f, 0.f, 0.f};
    for (int ss = 0; ss < 8; ++ss) {
      s0 += *(const f32x4*)&pan[ss][boff];
      s1 += *(const f32x4*)&pan[ss][boff + 4];
    }
    float v[8];
#pragma unroll
    for (int e = 0; e < 4; ++e) { v[e] = s0[e]; v[4 + e] = s1[e]; }
    const int n = rb * 16 + rw;

    const int blk = seg == 1 ? (p * 6 + 2 + (n >> 7)) : (p * 6 + (n >> 7));
    u16* d = C.Wcat2 + ((size_t)blk << 15) + (size_t)k * 4096 +
             ((n >> 5) & 3) * 512 + ((n >> 3) & 3) * 128 + (n & 7);
#pragma unroll
    for (int e = 0; e < 8; ++e) {
      const float val = v[e];
      const u16 hh = bf_rnd(val);
      d[(size_t)(ch * 8 + e) * 8] = hh;
      d[2048 + (size_t)(ch * 8 + e) * 8] = bf_rnd(val - bf_val(hh));
    }
  }
}

extern "C" void kernel_launch(void* const* d_in, const int* in_sizes, int n_in,
                              void* d_out, int out_size, void* d_ws,
                              size_t ws_size, hipStream_t stream) {
  const float* x = (const float*)d_in[0];
  const float* w1 = (const float*)d_in[1];
  const float* w2 = (const float*)d_in[2];

  float* out0 = (float*)d_out;
  float* out1 = out0 + 131072;
  float* out2 = out1 + 262144;

  char* W = (char*)d_ws;
  const size_t MB = 1ull << 20;
  u16* Vpk1 = (u16*)(W);
  u16* Wcat = (u16*)(W + 8 * MB);
  u16* Q1 = (u16*)(W + 14 * MB);
  u16* Q2 = (u16*)(W + 18 * MB);
  u16* Qc1 = (u16*)(W + 22 * MB);
  u16* P1h = (u16*)(W + 26 * MB);
  u16* P1l = (u16*)(W + 28 * MB);
  u16* P2h = (u16*)(W + 30 * MB);
  u16* P2l = (u16*)(W + 32 * MB);
  u16* Axh = (u16*)(W + 34 * MB);
  u16* Axl = (u16*)(W + 34 * MB + 262144);
  float* c1Z = (float*)(W + 35 * MB);
  u16* V1sqI = (u16*)(W + 36 * MB);
  u16* Wcat2 = (u16*)(W + 44 * MB);
  u16* V1pAh = (u16*)(W + 50 * MB);
  u16* V1pAl = (u16*)(W + 54 * MB);
  u16* UpAh = (u16*)(W + 58 * MB);
  u16* UpAl = (u16*)(W + 59 * MB);
  u16* BpAh = (u16*)(W + 60 * MB);
  u16* BpAl = (u16*)(W + 62 * MB);
  float* c1bZ = (float*)(W + 64 * MB);
  float* d2Z = (float*)(W + 65 * MB);
  u16* Z0h = (u16*)(W + 66 * MB);
  u16* Z0l = Z0h + 393216;
  u16* Z1h = Z0h + 786432;
  u16* Z1l = Z0h + 1179648;

  // D1: pack raw inputs (+ B planes)
  pack_in<<<2368, 256, 0, stream>>>(x, w1, w2, P1h, P1l, Q1, Qc1, P2h, P2l, Q2,
                                    Axh, Axl, Wcat, BpAh, BpAl, Z0h, Z0l, out0);

  // D2: compose single-step operators (+ operator A-planes)
  composeK<<<1408, 512, 0, stream>>>(P1h, P1l, Q1, P2h, P2l, Q2, Axh, Axl, Qc1,
                                     Vpk1, Wcat, V1pAh, V1pAl, UpAh, UpAl,
                                     Z0h, Z0l, c1Z);

  // D3: combo = seed step + compose2 (independent; one dispatch)
  {
    IArgs seed{Z0h, Z0l, Z1h, Z1l, Vpk1, Wcat, c1Z, nullptr,
               c1bZ, d2Z, out1, out2, 128};
    C2A c2{V1pAh, V1pAl, UpAh, UpAl, BpAh, BpAl, Vpk1, Wcat, V1sqI, Wcat2};
    combo<<<1472, 512, 0, stream>>>(seed, c2);
  }

  // D4..D12: 9 fused double-steps: (S2_t, S1_{t+1}) -> (S2_{t+2}, S1_{t+3})
  for (int tau = 0; tau < 9; ++tau) {
    const bool odd = tau & 1;
    IArgs ia{odd ? Z0h : Z1h, odd ? Z0l : Z1l,
             odd ? Z1h : Z0h, odd ? Z1l : Z0l,
             V1sqI, Wcat2, c1bZ, d2Z, nullptr, nullptr, out1, out2, 128};
    iter_k<<<192, 512, 0, stream>>>(ia, tau == 8 ? 1 : 0, 0);
  }

  // D13: final single g2 step: S2_20 = [S2_19 | S1_20] * Wcat -> out2
  {
    IArgs ia{Z0h, Z0l, Z1h, Z1l, Vpk1, Wcat, nullptr, nullptr,
             nullptr, nullptr, out1, out2, 0};
    iter_k<<<64, 512, 0, stream>>>(ia, 0, 1);
  }
}

// Round 16
// 322.725 us; speedup vs baseline: 1.4232x; 1.0987x over previous
//
#include <hip/hip_runtime.h>

typedef unsigned short u16;
typedef __attribute__((ext_vector_type(4))) float f32x4;
typedef __attribute__((ext_vector_type(8))) __bf16 bf16x8;
typedef __attribute__((ext_vector_type(8))) u16 u16x8;

#define ALPHA_F 0.1f

// Cl(3,0): e_a * e_c = (-1)^p e_{a^c}  [validated R1-R15]
__device__ __host__ constexpr bool SGN(int a, int c) {
  return ((((c & 1) & (((a >> 1) ^ (a >> 2)) & 1)) ^
           (((c >> 1) & 1) & ((a >> 2) & 1))) != 0);
}
__device__ __host__ constexpr float REVF(int c) {
  const int r = (c & 1) + ((c >> 1) & 1) + ((c >> 2) & 1);
  return (r >= 2) ? -1.f : 1.f;
}
__device__ __forceinline__ u16 bf_rnd(float f) {
  unsigned u = __float_as_uint(f);
  return (u16)((u + 0x7FFFu + ((u >> 16) & 1u)) >> 16);
}
__device__ __forceinline__ float bf_val(u16 h) {
  return __uint_as_float(((unsigned)h) << 16);
}
__device__ __forceinline__ f32x4 mf(bf16x8 a, bf16x8 b, f32x4 c) {
  return __builtin_amdgcn_mfma_f32_16x16x32_bf16(a, b, c, 0, 0, 0);
}
__device__ __forceinline__ bf16x8 negf(bf16x8 v) {
  u16x8 u = __builtin_bit_cast(u16x8, v);
  const u16x8 m = {0x8000, 0x8000, 0x8000, 0x8000, 0x8000, 0x8000, 0x8000, 0x8000};
  u = u ^ m;
  return __builtin_bit_cast(bf16x8, u);
}

// ===========================================================================
// D1: pack raw inputs — transposed thread mapping: each thread owns an
// r-octet for fixed (c, col) and emits contiguous u16x8 runs (coalesced).
// Formulas and rounding identical to R13-R15.
// ===========================================================================
__global__ __launch_bounds__(256) void pack_in(
    const float* __restrict__ x, const float* __restrict__ w1,
    const float* __restrict__ w2, u16* P1h, u16* P1l, u16* Q1, u16* Qc1,
    u16* P2h, u16* P2l, u16* Q2, u16* Axh, u16* Axl, u16* Vpk2,
    u16* BpAh, u16* BpAl, u16* Z0h, u16* Z0l, float* out0) {
  const int t = blockIdx.x * 256 + threadIdx.x;
  if (t < 131072) {  // Q1 + Qc1: thread = (c, ro, cc)
    const int cc = t & 511;          // cchigh*16+cclow, cc-fast for coalescing
    const int ro = (t >> 9) & 31;
    const int c = t >> 14;
    u16 h1[8], l1[8], hc[8], lc[8];
#pragma unroll
    for (int e = 0; e < 8; ++e) {
      const int r = ro * 8 + e;
      const float v = w1[((size_t)r * 512 + cc) * 8 + c];
      const float q1 = REVF(c) * v;
      const u16 hh = bf_rnd(q1);
      h1[e] = hh;
      l1[e] = bf_rnd(q1 - bf_val(hh));
      const float qc = ALPHA_F * q1;
      const u16 hh2 = bf_rnd(qc);
      hc[e] = hh2;
      lc[e] = bf_rnd(qc - bf_val(hh2));
    }
    const size_t qrun = (size_t)((cc >> 4) * 2 + (ro >> 4)) * 32768 +
                        ((ro >> 2) & 3) * 512 + (ro & 3) * 128 +
                        (cc & 15) * 8 + (size_t)c * 4096;
    *(u16x8*)&Q1[qrun] = *(u16x8*)h1;
    *(u16x8*)&Q1[qrun + 2048] = *(u16x8*)l1;
    *(u16x8*)&Qc1[qrun] = *(u16x8*)hc;
    *(u16x8*)&Qc1[qrun + 2048] = *(u16x8*)lc;
  } else if (t < 262144) {  // Q2 + Wcat-bottom + B-planes: thread = (c, ro, c2)
    const int u = t - 131072;
    const int c2 = u & 255;
    const int ro = (u >> 8) & 63;
    const int c = u >> 14;
    u16 h2[8], l2[8], hw[8], lw[8];
#pragma unroll
    for (int e = 0; e < 8; ++e) {
      const int r = ro * 8 + e;
      const float v = w2[((size_t)r * 256 + c2) * 8 + c];
      const float q2 = REVF(c) * v;
      const u16 hh = bf_rnd(q2);
      h2[e] = hh;
      l2[e] = bf_rnd(q2 - bf_val(hh));
      const float qw = ALPHA_F * q2;
      const u16 hh2 = bf_rnd(qw);
      hw[e] = hh2;
      lw[e] = bf_rnd(qw - bf_val(hh2));
    }
    const size_t tail = ((ro >> 2) & 3) * 512 + (ro & 3) * 128 +
                        (c2 & 15) * 8 + (size_t)c * 4096;
    const size_t qo = (size_t)((c2 >> 4) * 4 + (ro >> 4)) * 32768 + tail;
    const size_t wo = (size_t)((c2 >> 4) * 6 + 2 + (ro >> 4)) * 32768 + tail;
    *(u16x8*)&Q2[qo] = *(u16x8*)h2;
    *(u16x8*)&Q2[qo + 2048] = *(u16x8*)l2;
    *(u16x8*)&Vpk2[wo] = *(u16x8*)hw;
    *(u16x8*)&Vpk2[wo + 2048] = *(u16x8*)lw;
#pragma unroll
    for (int e = 0; e < 8; ++e) {  // B-plane (transposed; scalar, unavoidable)
      const int r = ro * 8 + e;
      const size_t bo = ((size_t)(c * 32 + (c2 >> 3)) * 512 + r) * 8 + (c2 & 7);
      BpAh[bo] = hw[e];
      BpAl[bo] = lw[e];
    }
  } else if (t < 393216) {  // P1c planes: thread = (a, ro, cc)
    const int u = t - 262144;
    const int cc = u & 511;
    const int ro = (u >> 9) & 31;
    const int a = u >> 14;
    u16 hh[8], ll[8];
#pragma unroll
    for (int e = 0; e < 8; ++e) {
      const int r = ro * 8 + e;
      const float v = w1[((size_t)r * 512 + cc) * 8 + a];
      const u16 h = bf_rnd(v);
      hh[e] = h;
      ll[e] = bf_rnd(v - bf_val(h));
    }
    const size_t o = ((size_t)(a * 32 + ro) * 512 + cc) * 8;
    *(u16x8*)&P1h[o] = *(u16x8*)hh;
    *(u16x8*)&P1l[o] = *(u16x8*)ll;
  } else if (t < 524288) {  // P2c planes: thread = (a, ro, c2)
    const int u = t - 393216;
    const int c2 = u & 255;
    const int ro = (u >> 8) & 63;
    const int a = u >> 14;
    u16 hh[8], ll[8];
#pragma unroll
    for (int e = 0; e < 8; ++e) {
      const int r = ro * 8 + e;
      const float v = w2[((size_t)r * 256 + c2) * 8 + a];
      const u16 h = bf_rnd(v);
      hh[e] = h;
      ll[e] = bf_rnd(v - bf_val(h));
    }
    const size_t o = ((size_t)(a * 64 + ro) * 256 + c2) * 8;
    *(u16x8*)&P2h[o] = *(u16x8*)hh;
    *(u16x8*)&P2l[o] = *(u16x8*)ll;
  } else if (t < 540672) {  // Axc planes: thread = (a, no, b)
    const int u = t - 524288;
    const int b = u & 63;
    const int no = (u >> 6) & 31;
    const int a = u >> 11;
    u16 hh[8], ll[8];
#pragma unroll
    for (int e = 0; e < 8; ++e) {
      const int n = no * 8 + e;
      const float v = x[((size_t)b * 256 + n) * 8 + a];
      const u16 h = bf_rnd(v);
      hh[e] = h;
      ll[e] = bf_rnd(v - bf_val(h));
    }
    const size_t o = ((size_t)(a * 32 + no) * 64 + b) * 8;
    *(u16x8*)&Axh[o] = *(u16x8*)hh;
    *(u16x8*)&Axl[o] = *(u16x8*)ll;
  } else if (t < 573440) {  // out0 = x
    const int u = t - 540672;
    ((float4*)out0)[u] = ((const float4*)x)[u];
  } else if (t < 606208) {  // Z0 S2-region zero
    const int u = t - 573440;
    const int hl = u >> 14, i = u & 16383;
    const int a = i >> 11, j = i & 2047;
    const u16x8 z = {0, 0, 0, 0, 0, 0, 0, 0};
    u16* Z = hl ? Z0l : Z0h;
    *(u16x8*)&Z[(size_t)a * 49152 + (size_t)j * 8] = z;
  }
}

// ===========================================================================
// D2: composeK — fat-row-32 tiles (R15-combo-seg0 pattern): halves V-image
// cross-block duplication. Per-output arithmetic identical to R14/R15.
//  [0,128):   seg1-fat: U compose (out 256x256, K=512), 16p x 8rq
//  [128,640): seg0-fat: V1 compose (out 512x512, K=256), 32p x 16rq
//  [640,768): seg2: c1 (out 64x512, K=256), 32p x 4rb (unchanged)
// ===========================================================================
__global__ __launch_bounds__(512) void composeK(
    const u16* __restrict__ P1h, const u16* __restrict__ P1l,
    const u16* __restrict__ Q1, const u16* __restrict__ P2h,
    const u16* __restrict__ P2l, const u16* __restrict__ Q2,
    const u16* __restrict__ Axh, const u16* __restrict__ Axl,
    const u16* __restrict__ Qc1, u16* Vpk1, u16* Vpk2,
    u16* V1pAh, u16* V1pAl, u16* UpAh, u16* UpAl,
    u16* Z0h, u16* Z0l, float* c1Z) {
  __shared__ float pan[8][2176];

  const int bid = blockIdx.x, tid = threadIdx.x;
  const int w = tid >> 6, l = tid & 63;
  const int lg = l >> 4, lm = l & 15;

  if (bid < 640) {
    // ---- fat segments (seg1: U, seg0: V1) ----
    const bool isU = bid < 128;
    const int p = isU ? (bid >> 3) : ((bid - 128) >> 4);
    const int rq = isU ? (bid & 7) : ((bid - 128) & 15);
    const int row0 = rq * 32 + lm, row1 = row0 + 16;
    const int NWf = isU ? 2 : 1;
    const int slmul = isU ? 4 : 2;
    const int KCf = isU ? 64 : 32;
    const int NROWf = isU ? 256 : 512;
    const u16* Vb = isU ? Q2 : Q1;
    const u16* Aph = isU ? P2h : P1h;
    const u16* Apl = isU ? P2l : P1l;

    f32x4 acc0[8], acc1[8];
#pragma unroll
    for (int k = 0; k < 8; ++k) {
      acc0[k] = f32x4{0.f, 0.f, 0.f, 0.f};
      acc1[k] = f32x4{0.f, 0.f, 0.f, 0.f};
    }
    for (int wi = 0; wi < NWf; ++wi) {
      const int n0 = w * (NWf * 32) + wi * 32;
      const int sl = n0 >> 7, hst = (n0 >> 5) & 3;
      const u16* Vimg = Vb + ((size_t)(p * slmul + sl) << 15) + hst * 512 +
                        lg * 128 + lm * 8;
      const int kc = (n0 >> 3) + lg;
      bf16x8 a0h[8], a0l[8], a1h[8], a1l[8];
#pragma unroll
      for (int a = 0; a < 8; ++a) {
        const size_t o0 = ((size_t)(a * KCf + kc) * NROWf + row0) * 8;
        const size_t o1 = ((size_t)(a * KCf + kc) * NROWf + row1) * 8;
        a0h[a] = *(const bf16x8*)(Aph + o0);
        a0l[a] = *(const bf16x8*)(Apl + o0);
        a1h[a] = *(const bf16x8*)(Aph + o1);
        a1l[a] = *(const bf16x8*)(Apl + o1);
      }
      __builtin_amdgcn_s_setprio(1);
#pragma unroll
      for (int c = 0; c < 8; ++c) {
        const bf16x8 vhp = *(const bf16x8*)(Vimg + (size_t)c * 4096);
        const bf16x8 vlp = *(const bf16x8*)(Vimg + (size_t)c * 4096 + 2048);
        const bf16x8 vhn = negf(vhp), vln = negf(vlp);
#pragma unroll
        for (int a = 0; a < 8; ++a) {
          const int k = a ^ c;
          const bf16x8 vh = SGN(a, c) ? vhn : vhp;
          const bf16x8 vl = SGN(a, c) ? vln : vlp;
          acc0[k] = mf(a0h[a], vh, acc0[k]);
          acc0[k] = mf(a0l[a], vh, acc0[k]);
          acc0[k] = mf(a0h[a], vl, acc0[k]);
          acc1[k] = mf(a1h[a], vh, acc1[k]);
          acc1[k] = mf(a1l[a], vh, acc1[k]);
          acc1[k] = mf(a1h[a], vl, acc1[k]);
        }
      }
      __builtin_amdgcn_s_setprio(0);
    }
#pragma unroll
    for (int rg = 0; rg < 2; ++rg) {
#pragma unroll
      for (int k = 0; k < 8; ++k)
#pragma unroll
        for (int q = 0; q < 4; ++q)
          pan[w][(k * 16 + lg * 4 + q) * 17 + lm] =
              rg ? acc1[k][q] : acc0[k][q];
      __syncthreads();
      if (tid < 256) {
        const int k = tid >> 5, rw = (tid >> 1) & 15, ch = tid & 1;
        const int boff = (k * 16 + rw) * 17 + ch * 8;
        f32x4 s0 = {0.f, 0.f, 0.f, 0.f}, s1 = {0.f, 0.f, 0.f, 0.f};
        for (int ss = 0; ss < 8; ++ss) {
          s0 += *(const f32x4*)&pan[ss][boff];
          s1 += *(const f32x4*)&pan[ss][boff + 4];
        }
        float v[8];
#pragma unroll
        for (int e = 0; e < 4; ++e) { v[e] = s0[e]; v[4 + e] = s1[e]; }
        const int n = rq * 32 + rg * 16 + rw;

        u16* base = isU ? Vpk2 : Vpk1;
        const int blk = (isU ? p * 6 : p * 4) + (n >> 7);
        u16* d = base + ((size_t)blk << 15) + (size_t)k * 4096 +
                 ((n >> 5) & 3) * 512 + ((n >> 3) & 3) * 128 + (n & 7);
        u16 ph[8], pl[8];
#pragma unroll
        for (int e = 0; e < 8; ++e) {
          const int m = p * 16 + ch * 8 + e;
          const float val =
              ((k == 0) && (n == m) ? 1.0f : 0.0f) - ALPHA_F * v[e];
          const u16 hh = bf_rnd(val);
          const u16 ll = bf_rnd(val - bf_val(hh));
          d[(size_t)(ch * 8 + e) * 8] = hh;
          d[2048 + (size_t)(ch * 8 + e) * 8] = ll;
          ph[e] = hh;
          pl[e] = ll;
        }
        if (isU) {
          const size_t po = (((size_t)k * 32 + p * 2 + ch) * 256 + n) * 8;
          *(u16x8*)&UpAh[po] = *(u16x8*)ph;
          *(u16x8*)&UpAl[po] = *(u16x8*)pl;
        } else {
          const size_t po = (((size_t)k * 64 + p * 2 + ch) * 512 + n) * 8;
          *(u16x8*)&V1pAh[po] = *(u16x8*)ph;
          *(u16x8*)&V1pAl[po] = *(u16x8*)pl;
        }
      }
      __syncthreads();
    }
    return;
  }

  // ---- seg2: c1 (unchanged logic) ----
  {
    const int idx = bid - 640;
    const int rb = idx & 3, p = idx >> 2;
    const int row = rb * 16 + lm;

    f32x4 acc[8];
#pragma unroll
    for (int k = 0; k < 8; ++k) acc[k] = f32x4{0.f, 0.f, 0.f, 0.f};

    const int n0 = w * 32;
    const int sl = n0 >> 7, hst = (n0 >> 5) & 3;
    const u16* Vimg = Qc1 + ((size_t)(p * 2 + sl) << 15) + hst * 512 +
                      lg * 128 + lm * 8;
    const int kc = (n0 >> 3) + lg;
    bf16x8 ah[8], al[8];
#pragma unroll
    for (int a = 0; a < 8; ++a) {
      const size_t o = ((size_t)(a * 32 + kc) * 64 + row) * 8;
      ah[a] = *(const bf16x8*)(Axh + o);
      al[a] = *(const bf16x8*)(Axl + o);
    }
    __builtin_amdgcn_s_setprio(1);
#pragma unroll
    for (int c = 0; c < 8; ++c) {
      const bf16x8 vhp = *(const bf16x8*)(Vimg + (size_t)c * 4096);
      const bf16x8 vlp = *(const bf16x8*)(Vimg + (size_t)c * 4096 + 2048);
      const bf16x8 vhn = negf(vhp), vln = negf(vlp);
#pragma unroll
      for (int a = 0; a < 8; ++a) {
        const int k = a ^ c;
        const bf16x8 vh = SGN(a, c) ? vhn : vhp;
        const bf16x8 vl = SGN(a, c) ? vln : vlp;
        acc[k] = mf(ah[a], vh, acc[k]);
        acc[k] = mf(al[a], vh, acc[k]);
        acc[k] = mf(ah[a], vl, acc[k]);
      }
    }
    __builtin_amdgcn_s_setprio(0);

#pragma unroll
    for (int k = 0; k < 8; ++k)
#pragma unroll
      for (int q = 0; q < 4; ++q)
        pan[w][(k * 16 + lg * 4 + q) * 17 + lm] = acc[k][q];
    __syncthreads();

    if (tid < 256) {
      const int k = tid >> 5, rw = (tid >> 1) & 15, ch = tid & 1;
      const int boff = (k * 16 + rw) * 17 + ch * 8;
      f32x4 s0 = {0.f, 0.f, 0.f, 0.f}, s1 = {0.f, 0.f, 0.f, 0.f};
      for (int ss = 0; ss < 8; ++ss) {
        s0 += *(const f32x4*)&pan[ss][boff];
        s1 += *(const f32x4*)&pan[ss][boff + 4];
      }
      float v[8];
#pragma unroll
      for (int e = 0; e < 4; ++e) { v[e] = s0[e]; v[4 + e] = s1[e]; }
      const int b = rb * 16 + rw;
      float* cp_ = c1Z + (((size_t)k * 64 + p * 2 + ch) * 64 + b) * 8;
      u16x8 h8, l8;
#pragma unroll
      for (int e = 0; e < 8; ++e) {
        cp_[e] = v[e];
        const u16 hh = bf_rnd(v[e]);
        h8[e] = hh;
        l8[e] = bf_rnd(v[e] - bf_val(hh));
      }
      const size_t zo = (((size_t)k * 96 + 32 + p * 2 + ch) * 64 + b) * 8;
      *(u16x8*)&Z0h[zo] = h8;
      *(u16x8*)&Z0l[zo] = l8;
    }
  }
}

// ===========================================================================
// Main-loop iter body (R14/R15-validated, verbatim).
// ===========================================================================
struct IArgs {
  const u16 *Zch, *Zcl;
  u16 *Znh, *Znl;
  const u16 *V1, *V2;
  const float *add1, *add2;
  float *oa1, *oa2;
  float *out1, *out2;
  int n_g1;
};

template <bool G1>
__device__ __forceinline__ void iter_body(const IArgs& A, int vbid, int t18,
                                          int fin, float (*pan)[2176]) {
  const int tid = threadIdx.x;
  const int w = tid >> 6, l = tid & 63;
  const int lg = l >> 4, lm = l & 15;
  const int rb = G1 ? vbid : vbid - A.n_g1;
  constexpr int NPAN = G1 ? 32 : 16;
  const int p = rb & (NPAN - 1);
  const int bh = rb / NPAN;
  const int b0 = bh * 16;
  constexpr int KW = G1 ? 64 : 96;
  constexpr int NW = G1 ? 2 : 3;
  constexpr int acb0 = G1 ? 32 : 0;
  constexpr int slmul = G1 ? 4 : 6;
  const u16* Vb = G1 ? A.V1 : A.V2;

  f32x4 acc[8];
#pragma unroll
  for (int k = 0; k < 8; ++k) acc[k] = f32x4{0.f, 0.f, 0.f, 0.f};

#pragma unroll
  for (int wi = 0; wi < NW; ++wi) {
    const int n0 = w * KW + wi * 32;
    const int sl = n0 >> 7, hst = (n0 >> 5) & 3;
    const u16* Vimg = Vb + ((size_t)(p * slmul + sl) << 15) + hst * 512 +
                      lg * 128 + lm * 8;
    const size_t ao = ((size_t)(acb0 + (n0 >> 3) + lg) * 64 + b0 + lm) * 8;
    bf16x8 ah[8], al[8];
#pragma unroll
    for (int a = 0; a < 8; ++a) {
      ah[a] = *(const bf16x8*)(A.Zch + (size_t)a * 49152 + ao);
      al[a] = *(const bf16x8*)(A.Zcl + (size_t)a * 49152 + ao);
    }
    __builtin_amdgcn_s_setprio(1);
#pragma unroll
    for (int c = 0; c < 8; ++c) {
      const bf16x8 vhp = *(const bf16x8*)(Vimg + (size_t)c * 4096);
      const bf16x8 vlp = *(const bf16x8*)(Vimg + (size_t)c * 4096 + 2048);
      const bf16x8 vhn = negf(vhp), vln = negf(vlp);
#pragma unroll
      for (int a = 0; a < 8; ++a) {
        const int k = a ^ c;
        const bf16x8 vh = SGN(a, c) ? vhn : vhp;
        const bf16x8 vl = SGN(a, c) ? vln : vlp;
        acc[k] = mf(ah[a], vh, acc[k]);
        acc[k] = mf(al[a], vh, acc[k]);
        acc[k] = mf(ah[a], vl, acc[k]);
      }
    }
    __builtin_amdgcn_s_setprio(0);
  }

#pragma unroll
  for (int k = 0; k < 8; ++k)
#pragma unroll
    for (int q = 0; q < 4; ++q)
      pan[w][(k * 16 + lg * 4 + q) * 17 + lm] = acc[k][q];
  __syncthreads();

  if (tid < 256) {
    const int k = tid >> 5, row = (tid >> 1) & 15, ch = tid & 1;
    const int boff = (k * 16 + row) * 17 + ch * 8;
    f32x4 s0 = {0.f, 0.f, 0.f, 0.f}, s1 = {0.f, 0.f, 0.f, 0.f};
    for (int ss = 0; ss < 8; ++ss) {
      s0 += *(const f32x4*)&pan[ss][boff];
      s1 += *(const f32x4*)&pan[ss][boff + 4];
    }
    const int b = b0 + row;
    if constexpr (G1) {
      if (A.add1) {
        const float* ca = A.add1 + (((size_t)k * 64 + p * 2 + ch) * 64 + b) * 8;
        s0 += *(const f32x4*)ca;
        s1 += *(const f32x4*)(ca + 4);
      }
    } else {
      if (A.add2) {
        const float* ca = A.add2 + (((size_t)k * 32 + p * 2 + ch) * 64 + b) * 8;
        s0 += *(const f32x4*)ca;
        s1 += *(const f32x4*)(ca + 4);
      }
    }
    float v[8];
#pragma unroll
    for (int e = 0; e < 4; ++e) { v[e] = s0[e]; v[4 + e] = s1[e]; }
    if constexpr (G1) {
      if (A.oa1) {
        float* q = A.oa1 + (((size_t)k * 64 + p * 2 + ch) * 64 + b) * 8;
#pragma unroll
        for (int e = 0; e < 8; ++e) q[e] = v[e];
      }
    } else {
      if (A.oa2) {
        float* q = A.oa2 + (((size_t)k * 32 + p * 2 + ch) * 64 + b) * 8;
#pragma unroll
        for (int e = 0; e < 8; ++e) q[e] = v[e];
      }
    }
    if (!fin) {
      u16x8 h8, l8;
#pragma unroll
      for (int e = 0; e < 8; ++e) {
        const u16 hh = bf_rnd(v[e]);
        h8[e] = hh;
        l8[e] = bf_rnd(v[e] - bf_val(hh));
      }
      const size_t zo =
          (((size_t)k * 96 + (G1 ? 32 : 0) + p * 2 + ch) * 64 + b) * 8;
      *(u16x8*)&A.Znh[zo] = h8;
      *(u16x8*)&A.Znl[zo] = l8;
    }
    if constexpr (G1) {
      if (t18) {
#pragma unroll
        for (int e = 0; e < 8; ++e)
          A.out1[((size_t)b * 512 + p * 16 + ch * 8 + e) * 8 + k] = v[e];
      }
    } else {
      if (fin) {
#pragma unroll
        for (int e = 0; e < 8; ++e)
          A.out2[((size_t)b * 256 + p * 16 + ch * 8 + e) * 8 + k] = v[e];
      }
    }
  }
}

__global__ __launch_bounds__(512, 2) void iter_k(IArgs A, int t18, int fin) {
  __shared__ float pan[8][2176];
  if ((int)blockIdx.x < A.n_g1) iter_body<true>(A, blockIdx.x, t18, fin, pan);
  else iter_body<false>(A, blockIdx.x, t18, fin, pan);
}

// ===========================================================================
// D3: combo = seed step + compose2 (R15-validated, verbatim).
// ===========================================================================
struct C2A {
  const u16 *V1pAh, *V1pAl, *UpAh, *UpAl, *BpAh, *BpAl;
  const u16 *Vpk1, *Wcat;
  u16 *V1sqI, *Wcat2;
};

__global__ __launch_bounds__(512) void combo(IArgs S, C2A C) {
  __shared__ float pan[8][2176];
  const int bid = blockIdx.x, tid = threadIdx.x;

  if (bid < 192) {  // seed step
    if (bid < S.n_g1) iter_body<true>(S, bid, 0, 0, pan);
    else iter_body<false>(S, bid, 0, 0, pan);
    return;
  }
  const int cb = bid - 192;
  const int w = tid >> 6, l = tid & 63;
  const int lg = l >> 4, lm = l & 15;

  if (cb < 512) {
    // ---- seg0: V1sq, 32-row tiles ----
    const int p = cb >> 4, rq = cb & 15;
    const int row0 = rq * 32 + lm, row1 = row0 + 16;
    f32x4 acc0[8], acc1[8];
#pragma unroll
    for (int k = 0; k < 8; ++k) {
      acc0[k] = f32x4{0.f, 0.f, 0.f, 0.f};
      acc1[k] = f32x4{0.f, 0.f, 0.f, 0.f};
    }
#pragma unroll
    for (int wi = 0; wi < 2; ++wi) {
      const int g = w * 2 + wi;
      const u16* Vimg = C.Vpk1 + ((size_t)(p * 4 + (g >> 2)) << 15) +
                        (g & 3) * 512 + lg * 128 + lm * 8;
      const int kc = g * 4 + lg;
      bf16x8 a0h[8], a0l[8], a1h[8], a1l[8];
#pragma unroll
      for (int a = 0; a < 8; ++a) {
        const size_t o0 = ((size_t)(a * 64 + kc) * 512 + row0) * 8;
        const size_t o1 = ((size_t)(a * 64 + kc) * 512 + row1) * 8;
        a0h[a] = *(const bf16x8*)(C.V1pAh + o0);
        a0l[a] = *(const bf16x8*)(C.V1pAl + o0);
        a1h[a] = *(const bf16x8*)(C.V1pAh + o1);
        a1l[a] = *(const bf16x8*)(C.V1pAl + o1);
      }
      __builtin_amdgcn_s_setprio(1);
#pragma unroll
      for (int c = 0; c < 8; ++c) {
        const bf16x8 vhp = *(const bf16x8*)(Vimg + (size_t)c * 4096);
        const bf16x8 vlp = *(const bf16x8*)(Vimg + (size_t)c * 4096 + 2048);
        const bf16x8 vhn = negf(vhp), vln = negf(vlp);
#pragma unroll
        for (int a = 0; a < 8; ++a) {
          const int k = a ^ c;
          const bf16x8 vh = SGN(a, c) ? vhn : vhp;
          const bf16x8 vl = SGN(a, c) ? vln : vlp;
          acc0[k] = mf(a0h[a], vh, acc0[k]);
          acc0[k] = mf(a0l[a], vh, acc0[k]);
          acc0[k] = mf(a0h[a], vl, acc0[k]);
          acc1[k] = mf(a1h[a], vh, acc1[k]);
          acc1[k] = mf(a1l[a], vh, acc1[k]);
          acc1[k] = mf(a1h[a], vl, acc1[k]);
        }
      }
      __builtin_amdgcn_s_setprio(0);
    }
#pragma unroll
    for (int rg = 0; rg < 2; ++rg) {
#pragma unroll
      for (int k = 0; k < 8; ++k)
#pragma unroll
        for (int q = 0; q < 4; ++q)
          pan[w][(k * 16 + lg * 4 + q) * 17 + lm] =
              rg ? acc1[k][q] : acc0[k][q];
      __syncthreads();
      if (tid < 256) {
        const int k = tid >> 5, rw = (tid >> 1) & 15, ch = tid & 1;
        const int boff = (k * 16 + rw) * 17 + ch * 8;
        f32x4 s0 = {0.f, 0.f, 0.f, 0.f}, s1 = {0.f, 0.f, 0.f, 0.f};
        for (int ss = 0; ss < 8; ++ss) {
          s0 += *(const f32x4*)&pan[ss][boff];
          s1 += *(const f32x4*)&pan[ss][boff + 4];
        }
        float v[8];
#pragma unroll
        for (int e = 0; e < 4; ++e) { v[e] = s0[e]; v[4 + e] = s1[e]; }
        const int n = rq * 32 + rg * 16 + rw;
        const int blk = p * 4 + (n >> 7);
        u16* d = C.V1sqI + ((size_t)blk << 15) + (size_t)k * 4096 +
                 ((n >> 5) & 3) * 512 + ((n >> 3) & 3) * 128 + (n & 7);
#pragma unroll
        for (int e = 0; e < 8; ++e) {
          const float val = v[e];
          const u16 hh = bf_rnd(val);
          d[(size_t)(ch * 8 + e) * 8] = hh;
          d[2048 + (size_t)(ch * 8 + e) * 8] = bf_rnd(val - bf_val(hh));
        }
      }
      __syncthreads();
    }
    return;
  }

  // ---- seg1 / seg2 ----
  int seg, rb, p;
  if (cb < 1024) { seg = 1; rb = (cb - 512) & 31; p = (cb - 512) >> 5; }
  else { seg = 2; rb = (cb - 1024) & 15; p = (cb - 1024) >> 4; }
  const int nwin = seg == 1 ? 3 : 1;
  const int row = rb * 16 + lm;

  f32x4 acc[8];
#pragma unroll
  for (int k = 0; k < 8; ++k) acc[k] = f32x4{0.f, 0.f, 0.f, 0.f};

  for (int wi = 0; wi < nwin; ++wi) {
    const int g = w * nwin + wi;
    const u16 *Aph, *Apl;
    int AKC, AR, kcb;
    const u16* Vimg;
    if (seg == 1) {
      if (g < 8) {
        Aph = C.BpAh; Apl = C.BpAl; AKC = 32; AR = 512; kcb = g * 4;
        Vimg = C.Wcat + ((size_t)(p * 6 + (g >> 2)) << 15) + (g & 3) * 512;
      } else {
        const int g2_ = g - 8;
        Aph = C.V1pAh; Apl = C.V1pAl; AKC = 64; AR = 512; kcb = g2_ * 4;
        Vimg = C.Wcat + ((size_t)(p * 6 + 2 + (g2_ >> 2)) << 15) + (g2_ & 3) * 512;
      }
    } else {
      Aph = C.UpAh; Apl = C.UpAl; AKC = 32; AR = 256; kcb = g * 4;
      Vimg = C.Wcat + ((size_t)(p * 6 + (g >> 2)) << 15) + (g & 3) * 512;
    }
    Vimg += lg * 128 + lm * 8;
    const int kc = kcb + lg;
    bf16x8 ah[8], al[8];
#pragma unroll
    for (int a = 0; a < 8; ++a) {
      const size_t o = ((size_t)(a * AKC + kc) * AR + row) * 8;
      ah[a] = *(const bf16x8*)(Aph + o);
      al[a] = *(const bf16x8*)(Apl + o);
    }
    __builtin_amdgcn_s_setprio(1);
#pragma unroll
    for (int c = 0; c < 8; ++c) {
      const bf16x8 vhp = *(const bf16x8*)(Vimg + (size_t)c * 4096);
      const bf16x8 vlp = *(const bf16x8*)(Vimg + (size_t)c * 4096 + 2048);
      const bf16x8 vhn = negf(vhp), vln = negf(vlp);
#pragma unroll
      for (int a = 0; a < 8; ++a) {
        const int k = a ^ c;
        const bf16x8 vh = SGN(a, c) ? vhn : vhp;
        const bf16x8 vl = SGN(a, c) ? vln : vlp;
        acc[k] = mf(ah[a], vh, acc[k]);
        acc[k] = mf(al[a], vh, acc[k]);
        acc[k] = mf(ah[a], vl, acc[k]);
      }
    }
    __builtin_amdgcn_s_setprio(0);
  }

#pragma unroll
  for (int k = 0; k < 8; ++k)
#pragma unroll
    for (int q = 0; q < 4; ++q)
      pan[w][(k * 16 + lg * 4 + q) * 17 + lm] = acc[k][q];
  __syncthreads();

  if (tid < 256) {
    const int k = tid >> 5, rw = (tid >> 1) & 15, ch = tid & 1;
    const int boff = (k * 16 + rw) * 17 + ch * 8;
    f32x4 s0 = {0.f, 0.f, 0.f, 0.f}, s1 = {0.f, 0.f, 0.f, 0.f};
    for (int ss = 0; ss < 8; ++ss) {
      s0 += *(const f32x4*)&pan[ss][boff];
      s1 += *(const f32x4*)&pan[ss][boff + 4];
    }
    float v[8];
#pragma unroll
    for (int e = 0; e < 4; ++e) { v[e] = s0[e]; v[4 + e] = s1[e]; }
    const int n = rb * 16 + rw;

    const int blk = seg == 1 ? (p * 6 + 2 + (n >> 7)) : (p * 6 + (n >> 7));
    u16* d = C.Wcat2 + ((size_t)blk << 15) + (size_t)k * 4096 +
             ((n >> 5) & 3) * 512 + ((n >> 3) & 3) * 128 + (n & 7);
#pragma unroll
    for (int e = 0; e < 8; ++e) {
      const float val = v[e];
      const u16 hh = bf_rnd(val);
      d[(size_t)(ch * 8 + e) * 8] = hh;
      d[2048 + (size_t)(ch * 8 + e) * 8] = bf_rnd(val - bf_val(hh));
    }
  }
}

extern "C" void kernel_launch(void* const* d_in, const int* in_sizes, int n_in,
                              void* d_out, int out_size, void* d_ws,
                              size_t ws_size, hipStream_t stream) {
  const float* x = (const float*)d_in[0];
  const float* w1 = (const float*)d_in[1];
  const float* w2 = (const float*)d_in[2];

  float* out0 = (float*)d_out;
  float* out1 = out0 + 131072;
  float* out2 = out1 + 262144;

  char* W = (char*)d_ws;
  const size_t MB = 1ull << 20;
  u16* Vpk1 = (u16*)(W);
  u16* Wcat = (u16*)(W + 8 * MB);
  u16* Q1 = (u16*)(W + 14 * MB);
  u16* Q2 = (u16*)(W + 18 * MB);
  u16* Qc1 = (u16*)(W + 22 * MB);
  u16* P1h = (u16*)(W + 26 * MB);
  u16* P1l = (u16*)(W + 28 * MB);
  u16* P2h = (u16*)(W + 30 * MB);
  u16* P2l = (u16*)(W + 32 * MB);
  u16* Axh = (u16*)(W + 34 * MB);
  u16* Axl = (u16*)(W + 34 * MB + 262144);
  float* c1Z = (float*)(W + 35 * MB);
  u16* V1sqI = (u16*)(W + 36 * MB);
  u16* Wcat2 = (u16*)(W + 44 * MB);
  u16* V1pAh = (u16*)(W + 50 * MB);
  u16* V1pAl = (u16*)(W + 54 * MB);
  u16* UpAh = (u16*)(W + 58 * MB);
  u16* UpAl = (u16*)(W + 59 * MB);
  u16* BpAh = (u16*)(W + 60 * MB);
  u16* BpAl = (u16*)(W + 62 * MB);
  float* c1bZ = (float*)(W + 64 * MB);
  float* d2Z = (float*)(W + 65 * MB);
  u16* Z0h = (u16*)(W + 66 * MB);
  u16* Z0l = Z0h + 393216;
  u16* Z1h = Z0h + 786432;
  u16* Z1l = Z0h + 1179648;

  // D1: pack raw inputs (+ B planes)
  pack_in<<<2368, 256, 0, stream>>>(x, w1, w2, P1h, P1l, Q1, Qc1, P2h, P2l, Q2,
                                    Axh, Axl, Wcat, BpAh, BpAl, Z0h, Z0l, out0);

  // D2: compose single-step operators (fat-row tiles)
  composeK<<<768, 512, 0, stream>>>(P1h, P1l, Q1, P2h, P2l, Q2, Axh, Axl, Qc1,
                                    Vpk1, Wcat, V1pAh, V1pAl, UpAh, UpAl,
                                    Z0h, Z0l, c1Z);

  // D3: combo = seed step + compose2
  {
    IArgs seed{Z0h, Z0l, Z1h, Z1l, Vpk1, Wcat, c1Z, nullptr,
               c1bZ, d2Z, out1, out2, 128};
    C2A c2{V1pAh, V1pAl, UpAh, UpAl, BpAh, BpAl, Vpk1, Wcat, V1sqI, Wcat2};
    combo<<<1472, 512, 0, stream>>>(seed, c2);
  }

  // D4..D12: 9 fused double-steps
  for (int tau = 0; tau < 9; ++tau) {
    const bool odd = tau & 1;
    IArgs ia{odd ? Z0h : Z1h, odd ? Z0l : Z1l,
             odd ? Z1h : Z0h, odd ? Z1l : Z0l,
             V1sqI, Wcat2, c1bZ, d2Z, nullptr, nullptr, out1, out2, 128};
    iter_k<<<192, 512, 0, stream>>>(ia, tau == 8 ? 1 : 0, 0);
  }

  // D13: final single g2 step -> out2
  {
    IArgs ia{Z0h, Z0l, Z1h, Z1l, Vpk1, Wcat, nullptr, nullptr,
             nullptr, nullptr, out1, out2, 0};
    iter_k<<<64, 512, 0, stream>>>(ia, 0, 1);
  }
}

// Round 17
// 307.983 us; speedup vs baseline: 1.4913x; 1.0479x over previous
//
#include <hip/hip_runtime.h>

typedef unsigned short u16;
typedef __attribute__((ext_vector_type(4))) float f32x4;
typedef __attribute__((ext_vector_type(8))) __bf16 bf16x8;
typedef __attribute__((ext_vector_type(8))) u16 u16x8;

#define ALPHA_F 0.1f

// Cl(3,0): e_a * e_c = (-1)^p e_{a^c}  [validated R1-R16]
__device__ __host__ constexpr bool SGN(int a, int c) {
  return ((((c & 1) & (((a >> 1) ^ (a >> 2)) & 1)) ^
           (((c >> 1) & 1) & ((a >> 2) & 1))) != 0);
}
__device__ __host__ constexpr float REVF(int c) {
  const int r = (c & 1) + ((c >> 1) & 1) + ((c >> 2) & 1);
  return (r >= 2) ? -1.f : 1.f;
}
__device__ __forceinline__ u16 bf_rnd(float f) {
  unsigned u = __float_as_uint(f);
  return (u16)((u + 0x7FFFu + ((u >> 16) & 1u)) >> 16);
}
__device__ __forceinline__ float bf_val(u16 h) {
  return __uint_as_float(((unsigned)h) << 16);
}
__device__ __forceinline__ f32x4 mf(bf16x8 a, bf16x8 b, f32x4 c) {
  return __builtin_amdgcn_mfma_f32_16x16x32_bf16(a, b, c, 0, 0, 0);
}
__device__ __forceinline__ bf16x8 negf(bf16x8 v) {
  u16x8 u = __builtin_bit_cast(u16x8, v);
  const u16x8 m = {0x8000, 0x8000, 0x8000, 0x8000, 0x8000, 0x8000, 0x8000, 0x8000};
  u = u ^ m;
  return __builtin_bit_cast(bf16x8, u);
}

// ===========================================================================
// D1: pack raw inputs (validated R16). UNCHANGED.
// ===========================================================================
__global__ __launch_bounds__(256) void pack_in(
    const float* __restrict__ x, const float* __restrict__ w1,
    const float* __restrict__ w2, u16* P1h, u16* P1l, u16* Q1, u16* Qc1,
    u16* P2h, u16* P2l, u16* Q2, u16* Axh, u16* Axl, u16* Vpk2,
    u16* BpAh, u16* BpAl, u16* Z0h, u16* Z0l, float* out0) {
  const int t = blockIdx.x * 256 + threadIdx.x;
  if (t < 131072) {
    const int cc = t & 511;
    const int ro = (t >> 9) & 31;
    const int c = t >> 14;
    u16 h1[8], l1[8], hc[8], lc[8];
#pragma unroll
    for (int e = 0; e < 8; ++e) {
      const int r = ro * 8 + e;
      const float v = w1[((size_t)r * 512 + cc) * 8 + c];
      const float q1 = REVF(c) * v;
      const u16 hh = bf_rnd(q1);
      h1[e] = hh;
      l1[e] = bf_rnd(q1 - bf_val(hh));
      const float qc = ALPHA_F * q1;
      const u16 hh2 = bf_rnd(qc);
      hc[e] = hh2;
      lc[e] = bf_rnd(qc - bf_val(hh2));
    }
    const size_t qrun = (size_t)((cc >> 4) * 2 + (ro >> 4)) * 32768 +
                        ((ro >> 2) & 3) * 512 + (ro & 3) * 128 +
                        (cc & 15) * 8 + (size_t)c * 4096;
    *(u16x8*)&Q1[qrun] = *(u16x8*)h1;
    *(u16x8*)&Q1[qrun + 2048] = *(u16x8*)l1;
    *(u16x8*)&Qc1[qrun] = *(u16x8*)hc;
    *(u16x8*)&Qc1[qrun + 2048] = *(u16x8*)lc;
  } else if (t < 262144) {
    const int u = t - 131072;
    const int c2 = u & 255;
    const int ro = (u >> 8) & 63;
    const int c = u >> 14;
    u16 h2[8], l2[8], hw[8], lw[8];
#pragma unroll
    for (int e = 0; e < 8; ++e) {
      const int r = ro * 8 + e;
      const float v = w2[((size_t)r * 256 + c2) * 8 + c];
      const float q2 = REVF(c) * v;
      const u16 hh = bf_rnd(q2);
      h2[e] = hh;
      l2[e] = bf_rnd(q2 - bf_val(hh));
      const float qw = ALPHA_F * q2;
      const u16 hh2 = bf_rnd(qw);
      hw[e] = hh2;
      lw[e] = bf_rnd(qw - bf_val(hh2));
    }
    const size_t tail = ((ro >> 2) & 3) * 512 + (ro & 3) * 128 +
                        (c2 & 15) * 8 + (size_t)c * 4096;
    const size_t qo = (size_t)((c2 >> 4) * 4 + (ro >> 4)) * 32768 + tail;
    const size_t wo = (size_t)((c2 >> 4) * 6 + 2 + (ro >> 4)) * 32768 + tail;
    *(u16x8*)&Q2[qo] = *(u16x8*)h2;
    *(u16x8*)&Q2[qo + 2048] = *(u16x8*)l2;
    *(u16x8*)&Vpk2[wo] = *(u16x8*)hw;
    *(u16x8*)&Vpk2[wo + 2048] = *(u16x8*)lw;
#pragma unroll
    for (int e = 0; e < 8; ++e) {
      const int r = ro * 8 + e;
      const size_t bo = ((size_t)(c * 32 + (c2 >> 3)) * 512 + r) * 8 + (c2 & 7);
      BpAh[bo] = hw[e];
      BpAl[bo] = lw[e];
    }
  } else if (t < 393216) {
    const int u = t - 262144;
    const int cc = u & 511;
    const int ro = (u >> 9) & 31;
    const int a = u >> 14;
    u16 hh[8], ll[8];
#pragma unroll
    for (int e = 0; e < 8; ++e) {
      const int r = ro * 8 + e;
      const float v = w1[((size_t)r * 512 + cc) * 8 + a];
      const u16 h = bf_rnd(v);
      hh[e] = h;
      ll[e] = bf_rnd(v - bf_val(h));
    }
    const size_t o = ((size_t)(a * 32 + ro) * 512 + cc) * 8;
    *(u16x8*)&P1h[o] = *(u16x8*)hh;
    *(u16x8*)&P1l[o] = *(u16x8*)ll;
  } else if (t < 524288) {
    const int u = t - 393216;
    const int c2 = u & 255;
    const int ro = (u >> 8) & 63;
    const int a = u >> 14;
    u16 hh[8], ll[8];
#pragma unroll
    for (int e = 0; e < 8; ++e) {
      const int r = ro * 8 + e;
      const float v = w2[((size_t)r * 256 + c2) * 8 + a];
      const u16 h = bf_rnd(v);
      hh[e] = h;
      ll[e] = bf_rnd(v - bf_val(h));
    }
    const size_t o = ((size_t)(a * 64 + ro) * 256 + c2) * 8;
    *(u16x8*)&P2h[o] = *(u16x8*)hh;
    *(u16x8*)&P2l[o] = *(u16x8*)ll;
  } else if (t < 540672) {
    const int u = t - 524288;
    const int b = u & 63;
    const int no = (u >> 6) & 31;
    const int a = u >> 11;
    u16 hh[8], ll[8];
#pragma unroll
    for (int e = 0; e < 8; ++e) {
      const int n = no * 8 + e;
      const float v = x[((size_t)b * 256 + n) * 8 + a];
      const u16 h = bf_rnd(v);
      hh[e] = h;
      ll[e] = bf_rnd(v - bf_val(h));
    }
    const size_t o = ((size_t)(a * 32 + no) * 64 + b) * 8;
    *(u16x8*)&Axh[o] = *(u16x8*)hh;
    *(u16x8*)&Axl[o] = *(u16x8*)ll;
  } else if (t < 573440) {
    const int u = t - 540672;
    ((float4*)out0)[u] = ((const float4*)x)[u];
  } else if (t < 606208) {
    const int u = t - 573440;
    const int hl = u >> 14, i = u & 16383;
    const int a = i >> 11, j = i & 2047;
    const u16x8 z = {0, 0, 0, 0, 0, 0, 0, 0};
    u16* Z = hl ? Z0l : Z0h;
    *(u16x8*)&Z[(size_t)a * 49152 + (size_t)j * 8] = z;
  }
}

// ===========================================================================
// D2: composeK — fat-row-32 tiles + half-window V-hoist (load scheduling
// only; per-output arithmetic identical to R14-R16).
// ===========================================================================
__global__ __launch_bounds__(512) void composeK(
    const u16* __restrict__ P1h, const u16* __restrict__ P1l,
    const u16* __restrict__ Q1, const u16* __restrict__ P2h,
    const u16* __restrict__ P2l, const u16* __restrict__ Q2,
    const u16* __restrict__ Axh, const u16* __restrict__ Axl,
    const u16* __restrict__ Qc1, u16* Vpk1, u16* Vpk2,
    u16* V1pAh, u16* V1pAl, u16* UpAh, u16* UpAl,
    u16* Z0h, u16* Z0l, float* c1Z) {
  __shared__ float pan[8][2176];

  const int bid = blockIdx.x, tid = threadIdx.x;
  const int w = tid >> 6, l = tid & 63;
  const int lg = l >> 4, lm = l & 15;

  if (bid < 640) {
    const bool isU = bid < 128;
    const int p = isU ? (bid >> 3) : ((bid - 128) >> 4);
    const int rq = isU ? (bid & 7) : ((bid - 128) & 15);
    const int row0 = rq * 32 + lm, row1 = row0 + 16;
    const int NWf = isU ? 2 : 1;
    const int slmul = isU ? 4 : 2;
    const int KCf = isU ? 64 : 32;
    const int NROWf = isU ? 256 : 512;
    const u16* Vb = isU ? Q2 : Q1;
    const u16* Aph = isU ? P2h : P1h;
    const u16* Apl = isU ? P2l : P1l;

    f32x4 acc0[8], acc1[8];
#pragma unroll
    for (int k = 0; k < 8; ++k) {
      acc0[k] = f32x4{0.f, 0.f, 0.f, 0.f};
      acc1[k] = f32x4{0.f, 0.f, 0.f, 0.f};
    }
    for (int wi = 0; wi < NWf; ++wi) {
      const int n0 = w * (NWf * 32) + wi * 32;
      const int sl = n0 >> 7, hst = (n0 >> 5) & 3;
      const u16* Vimg = Vb + ((size_t)(p * slmul + sl) << 15) + hst * 512 +
                        lg * 128 + lm * 8;
      const int kc = (n0 >> 3) + lg;
      bf16x8 a0h[8], a0l[8], a1h[8], a1l[8];
#pragma unroll
      for (int a = 0; a < 8; ++a) {
        const size_t o0 = ((size_t)(a * KCf + kc) * NROWf + row0) * 8;
        const size_t o1 = ((size_t)(a * KCf + kc) * NROWf + row1) * 8;
        a0h[a] = *(const bf16x8*)(Aph + o0);
        a0l[a] = *(const bf16x8*)(Apl + o0);
        a1h[a] = *(const bf16x8*)(Aph + o1);
        a1l[a] = *(const bf16x8*)(Apl + o1);
      }
#pragma unroll
      for (int half = 0; half < 2; ++half) {
        bf16x8 vh4[4], vl4[4];
#pragma unroll
        for (int cq = 0; cq < 4; ++cq) {
          vh4[cq] = *(const bf16x8*)(Vimg + (size_t)(half * 4 + cq) * 4096);
          vl4[cq] =
              *(const bf16x8*)(Vimg + (size_t)(half * 4 + cq) * 4096 + 2048);
        }
        __builtin_amdgcn_s_setprio(1);
#pragma unroll
        for (int cq = 0; cq < 4; ++cq) {
          const int c = half * 4 + cq;
          const bf16x8 vhp = vh4[cq], vlp = vl4[cq];
          const bf16x8 vhn = negf(vhp), vln = negf(vlp);
#pragma unroll
          for (int a = 0; a < 8; ++a) {
            const int k = a ^ c;
            const bf16x8 vh = SGN(a, c) ? vhn : vhp;
            const bf16x8 vl = SGN(a, c) ? vln : vlp;
            acc0[k] = mf(a0h[a], vh, acc0[k]);
            acc0[k] = mf(a0l[a], vh, acc0[k]);
            acc0[k] = mf(a0h[a], vl, acc0[k]);
            acc1[k] = mf(a1h[a], vh, acc1[k]);
            acc1[k] = mf(a1l[a], vh, acc1[k]);
            acc1[k] = mf(a1h[a], vl, acc1[k]);
          }
        }
        __builtin_amdgcn_s_setprio(0);
      }
    }
#pragma unroll
    for (int rg = 0; rg < 2; ++rg) {
#pragma unroll
      for (int k = 0; k < 8; ++k)
#pragma unroll
        for (int q = 0; q < 4; ++q)
          pan[w][(k * 16 + lg * 4 + q) * 17 + lm] =
              rg ? acc1[k][q] : acc0[k][q];
      __syncthreads();
      if (tid < 256) {
        const int k = tid >> 5, rw = (tid >> 1) & 15, ch = tid & 1;
        const int boff = (k * 16 + rw) * 17 + ch * 8;
        f32x4 s0 = {0.f, 0.f, 0.f, 0.f}, s1 = {0.f, 0.f, 0.f, 0.f};
        for (int ss = 0; ss < 8; ++ss) {
          s0 += *(const f32x4*)&pan[ss][boff];
          s1 += *(const f32x4*)&pan[ss][boff + 4];
        }
        float v[8];
#pragma unroll
        for (int e = 0; e < 4; ++e) { v[e] = s0[e]; v[4 + e] = s1[e]; }
        const int n = rq * 32 + rg * 16 + rw;

        u16* base = isU ? Vpk2 : Vpk1;
        const int blk = (isU ? p * 6 : p * 4) + (n >> 7);
        u16* d = base + ((size_t)blk << 15) + (size_t)k * 4096 +
                 ((n >> 5) & 3) * 512 + ((n >> 3) & 3) * 128 + (n & 7);
        u16 ph[8], pl[8];
#pragma unroll
        for (int e = 0; e < 8; ++e) {
          const int m = p * 16 + ch * 8 + e;
          const float val =
              ((k == 0) && (n == m) ? 1.0f : 0.0f) - ALPHA_F * v[e];
          const u16 hh = bf_rnd(val);
          const u16 ll = bf_rnd(val - bf_val(hh));
          d[(size_t)(ch * 8 + e) * 8] = hh;
          d[2048 + (size_t)(ch * 8 + e) * 8] = ll;
          ph[e] = hh;
          pl[e] = ll;
        }
        if (isU) {
          const size_t po = (((size_t)k * 32 + p * 2 + ch) * 256 + n) * 8;
          *(u16x8*)&UpAh[po] = *(u16x8*)ph;
          *(u16x8*)&UpAl[po] = *(u16x8*)pl;
        } else {
          const size_t po = (((size_t)k * 64 + p * 2 + ch) * 512 + n) * 8;
          *(u16x8*)&V1pAh[po] = *(u16x8*)ph;
          *(u16x8*)&V1pAl[po] = *(u16x8*)pl;
        }
      }
      __syncthreads();
    }
    return;
  }

  // ---- seg2: c1 (full V hoist) ----
  {
    const int idx = bid - 640;
    const int rb = idx & 3, p = idx >> 2;
    const int row = rb * 16 + lm;

    f32x4 acc[8];
#pragma unroll
    for (int k = 0; k < 8; ++k) acc[k] = f32x4{0.f, 0.f, 0.f, 0.f};

    const int n0 = w * 32;
    const int sl = n0 >> 7, hst = (n0 >> 5) & 3;
    const u16* Vimg = Qc1 + ((size_t)(p * 2 + sl) << 15) + hst * 512 +
                      lg * 128 + lm * 8;
    const int kc = (n0 >> 3) + lg;
    bf16x8 ah[8], al[8], vh8[8], vl8[8];
#pragma unroll
    for (int a = 0; a < 8; ++a) {
      const size_t o = ((size_t)(a * 32 + kc) * 64 + row) * 8;
      ah[a] = *(const bf16x8*)(Axh + o);
      al[a] = *(const bf16x8*)(Axl + o);
    }
#pragma unroll
    for (int c = 0; c < 8; ++c) {
      vh8[c] = *(const bf16x8*)(Vimg + (size_t)c * 4096);
      vl8[c] = *(const bf16x8*)(Vimg + (size_t)c * 4096 + 2048);
    }
    __builtin_amdgcn_s_setprio(1);
#pragma unroll
    for (int c = 0; c < 8; ++c) {
      const bf16x8 vhp = vh8[c], vlp = vl8[c];
      const bf16x8 vhn = negf(vhp), vln = negf(vlp);
#pragma unroll
      for (int a = 0; a < 8; ++a) {
        const int k = a ^ c;
        const bf16x8 vh = SGN(a, c) ? vhn : vhp;
        const bf16x8 vl = SGN(a, c) ? vln : vlp;
        acc[k] = mf(ah[a], vh, acc[k]);
        acc[k] = mf(al[a], vh, acc[k]);
        acc[k] = mf(ah[a], vl, acc[k]);
      }
    }
    __builtin_amdgcn_s_setprio(0);

#pragma unroll
    for (int k = 0; k < 8; ++k)
#pragma unroll
      for (int q = 0; q < 4; ++q)
        pan[w][(k * 16 + lg * 4 + q) * 17 + lm] = acc[k][q];
    __syncthreads();

    if (tid < 256) {
      const int k = tid >> 5, rw = (tid >> 1) & 15, ch = tid & 1;
      const int boff = (k * 16 + rw) * 17 + ch * 8;
      f32x4 s0 = {0.f, 0.f, 0.f, 0.f}, s1 = {0.f, 0.f, 0.f, 0.f};
      for (int ss = 0; ss < 8; ++ss) {
        s0 += *(const f32x4*)&pan[ss][boff];
        s1 += *(const f32x4*)&pan[ss][boff + 4];
      }
      float v[8];
#pragma unroll
      for (int e = 0; e < 4; ++e) { v[e] = s0[e]; v[4 + e] = s1[e]; }
      const int b = rb * 16 + rw;
      float* cp_ = c1Z + (((size_t)k * 64 + p * 2 + ch) * 64 + b) * 8;
      u16x8 h8, l8;
#pragma unroll
      for (int e = 0; e < 8; ++e) {
        cp_[e] = v[e];
        const u16 hh = bf_rnd(v[e]);
        h8[e] = hh;
        l8[e] = bf_rnd(v[e] - bf_val(hh));
      }
      const size_t zo = (((size_t)k * 96 + 32 + p * 2 + ch) * 64 + b) * 8;
      *(u16x8*)&Z0h[zo] = h8;
      *(u16x8*)&Z0l[zo] = l8;
    }
  }
}

// ===========================================================================
// Main-loop iter body — software-pipelined: per-window {16 A + 16 V} loads
// issued together before the MFMA cluster; next-window A prefetched during
// compute. Pure load scheduling; FP sequence identical to R14-R16.
// ===========================================================================
struct IArgs {
  const u16 *Zch, *Zcl;
  u16 *Znh, *Znl;
  const u16 *V1, *V2;
  const float *add1, *add2;
  float *oa1, *oa2;
  float *out1, *out2;
  int n_g1;
};

template <bool G1>
__device__ __forceinline__ void iter_body(const IArgs& A, int vbid, int t18,
                                          int fin, float (*pan)[2176]) {
  const int tid = threadIdx.x;
  const int w = tid >> 6, l = tid & 63;
  const int lg = l >> 4, lm = l & 15;
  const int rb = G1 ? vbid : vbid - A.n_g1;
  constexpr int NPAN = G1 ? 32 : 16;
  const int p = rb & (NPAN - 1);
  const int bh = rb / NPAN;
  const int b0 = bh * 16;
  constexpr int KW = G1 ? 64 : 96;
  constexpr int NW = G1 ? 2 : 3;
  constexpr int acb0 = G1 ? 32 : 0;
  constexpr int slmul = G1 ? 4 : 6;
  const u16* Vb = G1 ? A.V1 : A.V2;

  f32x4 acc[8];
#pragma unroll
  for (int k = 0; k < 8; ++k) acc[k] = f32x4{0.f, 0.f, 0.f, 0.f};

  auto LOADA = [&](int wi, bf16x8* h, bf16x8* lo) {
    const int n0 = w * KW + wi * 32;
    const size_t ao = ((size_t)(acb0 + (n0 >> 3) + lg) * 64 + b0 + lm) * 8;
#pragma unroll
    for (int a = 0; a < 8; ++a) {
      h[a] = *(const bf16x8*)(A.Zch + (size_t)a * 49152 + ao);
      lo[a] = *(const bf16x8*)(A.Zcl + (size_t)a * 49152 + ao);
    }
  };
  auto LOADV = [&](int wi, bf16x8* vhv, bf16x8* vlv) {
    const int n0 = w * KW + wi * 32;
    const int sl = n0 >> 7, hst = (n0 >> 5) & 3;
    const u16* Vimg = Vb + ((size_t)(p * slmul + sl) << 15) + hst * 512 +
                      lg * 128 + lm * 8;
#pragma unroll
    for (int c = 0; c < 8; ++c) {
      vhv[c] = *(const bf16x8*)(Vimg + (size_t)c * 4096);
      vlv[c] = *(const bf16x8*)(Vimg + (size_t)c * 4096 + 2048);
    }
  };
  auto COMP = [&](const bf16x8* h, const bf16x8* lo, const bf16x8* vhv,
                  const bf16x8* vlv) {
    __builtin_amdgcn_s_setprio(1);
#pragma unroll
    for (int c = 0; c < 8; ++c) {
      const bf16x8 vhp = vhv[c], vlp = vlv[c];
      const bf16x8 vhn = negf(vhp), vln = negf(vlp);
#pragma unroll
      for (int a = 0; a < 8; ++a) {
        const int k = a ^ c;
        const bf16x8 vh = SGN(a, c) ? vhn : vhp;
        const bf16x8 vl = SGN(a, c) ? vln : vlp;
        acc[k] = mf(h[a], vh, acc[k]);
        acc[k] = mf(lo[a], vh, acc[k]);
        acc[k] = mf(h[a], vl, acc[k]);
      }
    }
    __builtin_amdgcn_s_setprio(0);
  };

  bf16x8 ah[8], al[8], ph[8], pl[8], vh8[8], vl8[8];
  LOADA(0, ah, al);
  LOADV(0, vh8, vl8);
  if constexpr (NW > 1) LOADA(1, ph, pl);
  COMP(ah, al, vh8, vl8);
  if constexpr (NW > 1) {
    LOADV(1, vh8, vl8);
    if constexpr (NW > 2) LOADA(2, ah, al);
    COMP(ph, pl, vh8, vl8);
  }
  if constexpr (NW > 2) {
    LOADV(2, vh8, vl8);
    COMP(ah, al, vh8, vl8);
  }

#pragma unroll
  for (int k = 0; k < 8; ++k)
#pragma unroll
    for (int q = 0; q < 4; ++q)
      pan[w][(k * 16 + lg * 4 + q) * 17 + lm] = acc[k][q];
  __syncthreads();

  if (tid < 256) {
    const int k = tid >> 5, row = (tid >> 1) & 15, ch = tid & 1;
    const int boff = (k * 16 + row) * 17 + ch * 8;
    f32x4 s0 = {0.f, 0.f, 0.f, 0.f}, s1 = {0.f, 0.f, 0.f, 0.f};
    for (int ss = 0; ss < 8; ++ss) {
      s0 += *(const f32x4*)&pan[ss][boff];
      s1 += *(const f32x4*)&pan[ss][boff + 4];
    }
    const int b = b0 + row;
    if constexpr (G1) {
      if (A.add1) {
        const float* ca = A.add1 + (((size_t)k * 64 + p * 2 + ch) * 64 + b) * 8;
        s0 += *(const f32x4*)ca;
        s1 += *(const f32x4*)(ca + 4);
      }
    } else {
      if (A.add2) {
        const float* ca = A.add2 + (((size_t)k * 32 + p * 2 + ch) * 64 + b) * 8;
        s0 += *(const f32x4*)ca;
        s1 += *(const f32x4*)(ca + 4);
      }
    }
    float v[8];
#pragma unroll
    for (int e = 0; e < 4; ++e) { v[e] = s0[e]; v[4 + e] = s1[e]; }
    if constexpr (G1) {
      if (A.oa1) {
        float* q = A.oa1 + (((size_t)k * 64 + p * 2 + ch) * 64 + b) * 8;
#pragma unroll
        for (int e = 0; e < 8; ++e) q[e] = v[e];
      }
    } else {
      if (A.oa2) {
        float* q = A.oa2 + (((size_t)k * 32 + p * 2 + ch) * 64 + b) * 8;
#pragma unroll
        for (int e = 0; e < 8; ++e) q[e] = v[e];
      }
    }
    if (!fin) {
      u16x8 h8, l8;
#pragma unroll
      for (int e = 0; e < 8; ++e) {
        const u16 hh = bf_rnd(v[e]);
        h8[e] = hh;
        l8[e] = bf_rnd(v[e] - bf_val(hh));
      }
      const size_t zo =
          (((size_t)k * 96 + (G1 ? 32 : 0) + p * 2 + ch) * 64 + b) * 8;
      *(u16x8*)&A.Znh[zo] = h8;
      *(u16x8*)&A.Znl[zo] = l8;
    }
    if constexpr (G1) {
      if (t18) {
#pragma unroll
        for (int e = 0; e < 8; ++e)
          A.out1[((size_t)b * 512 + p * 16 + ch * 8 + e) * 8 + k] = v[e];
      }
    } else {
      if (fin) {
#pragma unroll
        for (int e = 0; e < 8; ++e)
          A.out2[((size_t)b * 256 + p * 16 + ch * 8 + e) * 8 + k] = v[e];
      }
    }
  }
}

__global__ __launch_bounds__(512) void iter_k(IArgs A, int t18, int fin) {
  __shared__ float pan[8][2176];
  if ((int)blockIdx.x < A.n_g1) iter_body<true>(A, blockIdx.x, t18, fin, pan);
  else iter_body<false>(A, blockIdx.x, t18, fin, pan);
}

// ===========================================================================
// D3: combo = seed + compose2, V-hoisted variants (arithmetic identical).
// ===========================================================================
struct C2A {
  const u16 *V1pAh, *V1pAl, *UpAh, *UpAl, *BpAh, *BpAl;
  const u16 *Vpk1, *Wcat;
  u16 *V1sqI, *Wcat2;
};

__global__ __launch_bounds__(512) void combo(IArgs S, C2A C) {
  __shared__ float pan[8][2176];
  const int bid = blockIdx.x, tid = threadIdx.x;

  if (bid < 192) {
    if (bid < S.n_g1) iter_body<true>(S, bid, 0, 0, pan);
    else iter_body<false>(S, bid, 0, 0, pan);
    return;
  }
  const int cb = bid - 192;
  const int w = tid >> 6, l = tid & 63;
  const int lg = l >> 4, lm = l & 15;

  if (cb < 512) {
    // ---- seg0: V1sq, 32-row tiles, half-window V hoist ----
    const int p = cb >> 4, rq = cb & 15;
    const int row0 = rq * 32 + lm, row1 = row0 + 16;
    f32x4 acc0[8], acc1[8];
#pragma unroll
    for (int k = 0; k < 8; ++k) {
      acc0[k] = f32x4{0.f, 0.f, 0.f, 0.f};
      acc1[k] = f32x4{0.f, 0.f, 0.f, 0.f};
    }
#pragma unroll
    for (int wi = 0; wi < 2; ++wi) {
      const int g = w * 2 + wi;
      const u16* Vimg = C.Vpk1 + ((size_t)(p * 4 + (g >> 2)) << 15) +
                        (g & 3) * 512 + lg * 128 + lm * 8;
      const int kc = g * 4 + lg;
      bf16x8 a0h[8], a0l[8], a1h[8], a1l[8];
#pragma unroll
      for (int a = 0; a < 8; ++a) {
        const size_t o0 = ((size_t)(a * 64 + kc) * 512 + row0) * 8;
        const size_t o1 = ((size_t)(a * 64 + kc) * 512 + row1) * 8;
        a0h[a] = *(const bf16x8*)(C.V1pAh + o0);
        a0l[a] = *(const bf16x8*)(C.V1pAl + o0);
        a1h[a] = *(const bf16x8*)(C.V1pAh + o1);
        a1l[a] = *(const bf16x8*)(C.V1pAl + o1);
      }
#pragma unroll
      for (int half = 0; half < 2; ++half) {
        bf16x8 vh4[4], vl4[4];
#pragma unroll
        for (int cq = 0; cq < 4; ++cq) {
          vh4[cq] = *(const bf16x8*)(Vimg + (size_t)(half * 4 + cq) * 4096);
          vl4[cq] =
              *(const bf16x8*)(Vimg + (size_t)(half * 4 + cq) * 4096 + 2048);
        }
        __builtin_amdgcn_s_setprio(1);
#pragma unroll
        for (int cq = 0; cq < 4; ++cq) {
          const int c = half * 4 + cq;
          const bf16x8 vhp = vh4[cq], vlp = vl4[cq];
          const bf16x8 vhn = negf(vhp), vln = negf(vlp);
#pragma unroll
          for (int a = 0; a < 8; ++a) {
            const int k = a ^ c;
            const bf16x8 vh = SGN(a, c) ? vhn : vhp;
            const bf16x8 vl = SGN(a, c) ? vln : vlp;
            acc0[k] = mf(a0h[a], vh, acc0[k]);
            acc0[k] = mf(a0l[a], vh, acc0[k]);
            acc0[k] = mf(a0h[a], vl, acc0[k]);
            acc1[k] = mf(a1h[a], vh, acc1[k]);
            acc1[k] = mf(a1l[a], vh, acc1[k]);
            acc1[k] = mf(a1h[a], vl, acc1[k]);
          }
        }
        __builtin_amdgcn_s_setprio(0);
      }
    }
#pragma unroll
    for (int rg = 0; rg < 2; ++rg) {
#pragma unroll
      for (int k = 0; k < 8; ++k)
#pragma unroll
        for (int q = 0; q < 4; ++q)
          pan[w][(k * 16 + lg * 4 + q) * 17 + lm] =
              rg ? acc1[k][q] : acc0[k][q];
      __syncthreads();
      if (tid < 256) {
        const int k = tid >> 5, rw = (tid >> 1) & 15, ch = tid & 1;
        const int boff = (k * 16 + rw) * 17 + ch * 8;
        f32x4 s0 = {0.f, 0.f, 0.f, 0.f}, s1 = {0.f, 0.f, 0.f, 0.f};
        for (int ss = 0; ss < 8; ++ss) {
          s0 += *(const f32x4*)&pan[ss][boff];
          s1 += *(const f32x4*)&pan[ss][boff + 4];
        }
        float v[8];
#pragma unroll
        for (int e = 0; e < 4; ++e) { v[e] = s0[e]; v[4 + e] = s1[e]; }
        const int n = rq * 32 + rg * 16 + rw;
        const int blk = p * 4 + (n >> 7);
        u16* d = C.V1sqI + ((size_t)blk << 15) + (size_t)k * 4096 +
                 ((n >> 5) & 3) * 512 + ((n >> 3) & 3) * 128 + (n & 7);
#pragma unroll
        for (int e = 0; e < 8; ++e) {
          const float val = v[e];
          const u16 hh = bf_rnd(val);
          d[(size_t)(ch * 8 + e) * 8] = hh;
          d[2048 + (size_t)(ch * 8 + e) * 8] = bf_rnd(val - bf_val(hh));
        }
      }
      __syncthreads();
    }
    return;
  }

  // ---- seg1 / seg2 (full V hoist per window) ----
  int seg, rb, p;
  if (cb < 1024) { seg = 1; rb = (cb - 512) & 31; p = (cb - 512) >> 5; }
  else { seg = 2; rb = (cb - 1024) & 15; p = (cb - 1024) >> 4; }
  const int nwin = seg == 1 ? 3 : 1;
  const int row = rb * 16 + lm;

  f32x4 acc[8];
#pragma unroll
  for (int k = 0; k < 8; ++k) acc[k] = f32x4{0.f, 0.f, 0.f, 0.f};

  for (int wi = 0; wi < nwin; ++wi) {
    const int g = w * nwin + wi;
    const u16 *Aph, *Apl;
    int AKC, AR, kcb;
    const u16* Vimg;
    if (seg == 1) {
      if (g < 8) {
        Aph = C.BpAh; Apl = C.BpAl; AKC = 32; AR = 512; kcb = g * 4;
        Vimg = C.Wcat + ((size_t)(p * 6 + (g >> 2)) << 15) + (g & 3) * 512;
      } else {
        const int g2_ = g - 8;
        Aph = C.V1pAh; Apl = C.V1pAl; AKC = 64; AR = 512; kcb = g2_ * 4;
        Vimg = C.Wcat + ((size_t)(p * 6 + 2 + (g2_ >> 2)) << 15) + (g2_ & 3) * 512;
      }
    } else {
      Aph = C.UpAh; Apl = C.UpAl; AKC = 32; AR = 256; kcb = g * 4;
      Vimg = C.Wcat + ((size_t)(p * 6 + (g >> 2)) << 15) + (g & 3) * 512;
    }
    Vimg += lg * 128 + lm * 8;
    const int kc = kcb + lg;
    bf16x8 ah[8], al[8], vh8[8], vl8[8];
#pragma unroll
    for (int a = 0; a < 8; ++a) {
      const size_t o = ((size_t)(a * AKC + kc) * AR + row) * 8;
      ah[a] = *(const bf16x8*)(Aph + o);
      al[a] = *(const bf16x8*)(Apl + o);
    }
#pragma unroll
    for (int c = 0; c < 8; ++c) {
      vh8[c] = *(const bf16x8*)(Vimg + (size_t)c * 4096);
      vl8[c] = *(const bf16x8*)(Vimg + (size_t)c * 4096 + 2048);
    }
    __builtin_amdgcn_s_setprio(1);
#pragma unroll
    for (int c = 0; c < 8; ++c) {
      const bf16x8 vhp = vh8[c], vlp = vl8[c];
      const bf16x8 vhn = negf(vhp), vln = negf(vlp);
#pragma unroll
      for (int a = 0; a < 8; ++a) {
        const int k = a ^ c;
        const bf16x8 vh = SGN(a, c) ? vhn : vhp;
        const bf16x8 vl = SGN(a, c) ? vln : vlp;
        acc[k] = mf(ah[a], vh, acc[k]);
        acc[k] = mf(al[a], vh, acc[k]);
        acc[k] = mf(ah[a], vl, acc[k]);
      }
    }
    __builtin_amdgcn_s_setprio(0);
  }

#pragma unroll
  for (int k = 0; k < 8; ++k)
#pragma unroll
    for (int q = 0; q < 4; ++q)
      pan[w][(k * 16 + lg * 4 + q) * 17 + lm] = acc[k][q];
  __syncthreads();

  if (tid < 256) {
    const int k = tid >> 5, rw = (tid >> 1) & 15, ch = tid & 1;
    const int boff = (k * 16 + rw) * 17 + ch * 8;
    f32x4 s0 = {0.f, 0.f, 0.f, 0.f}, s1 = {0.f, 0.f, 0.f, 0.f};
    for (int ss = 0; ss < 8; ++ss) {
      s0 += *(const f32x4*)&pan[ss][boff];
      s1 += *(const f32x4*)&pan[ss][boff + 4];
    }
    float v[8];
#pragma unroll
    for (int e = 0; e < 4; ++e) { v[e] = s0[e]; v[4 + e] = s1[e]; }
    const int n = rb * 16 + rw;

    const int blk = seg == 1 ? (p * 6 + 2 + (n >> 7)) : (p * 6 + (n >> 7));
    u16* d = C.Wcat2 + ((size_t)blk << 15) + (size_t)k * 4096 +
             ((n >> 5) & 3) * 512 + ((n >> 3) & 3) * 128 + (n & 7);
#pragma unroll
    for (int e = 0; e < 8; ++e) {
      const float val = v[e];
      const u16 hh = bf_rnd(val);
      d[(size_t)(ch * 8 + e) * 8] = hh;
      d[2048 + (size_t)(ch * 8 + e) * 8] = bf_rnd(val - bf_val(hh));
    }
  }
}

extern "C" void kernel_launch(void* const* d_in, const int* in_sizes, int n_in,
                              void* d_out, int out_size, void* d_ws,
                              size_t ws_size, hipStream_t stream) {
  const float* x = (const float*)d_in[0];
  const float* w1 = (const float*)d_in[1];
  const float* w2 = (const float*)d_in[2];

  float* out0 = (float*)d_out;
  float* out1 = out0 + 131072;
  float* out2 = out1 + 262144;

  char* W = (char*)d_ws;
  const size_t MB = 1ull << 20;
  u16* Vpk1 = (u16*)(W);
  u16* Wcat = (u16*)(W + 8 * MB);
  u16* Q1 = (u16*)(W + 14 * MB);
  u16* Q2 = (u16*)(W + 18 * MB);
  u16* Qc1 = (u16*)(W + 22 * MB);
  u16* P1h = (u16*)(W + 26 * MB);
  u16* P1l = (u16*)(W + 28 * MB);
  u16* P2h = (u16*)(W + 30 * MB);
  u16* P2l = (u16*)(W + 32 * MB);
  u16* Axh = (u16*)(W + 34 * MB);
  u16* Axl = (u16*)(W + 34 * MB + 262144);
  float* c1Z = (float*)(W + 35 * MB);
  u16* V1sqI = (u16*)(W + 36 * MB);
  u16* Wcat2 = (u16*)(W + 44 * MB);
  u16* V1pAh = (u16*)(W + 50 * MB);
  u16* V1pAl = (u16*)(W + 54 * MB);
  u16* UpAh = (u16*)(W + 58 * MB);
  u16* UpAl = (u16*)(W + 59 * MB);
  u16* BpAh = (u16*)(W + 60 * MB);
  u16* BpAl = (u16*)(W + 62 * MB);
  float* c1bZ = (float*)(W + 64 * MB);
  float* d2Z = (float*)(W + 65 * MB);
  u16* Z0h = (u16*)(W + 66 * MB);
  u16* Z0l = Z0h + 393216;
  u16* Z1h = Z0h + 786432;
  u16* Z1l = Z0h + 1179648;

  // D1: pack raw inputs (+ B planes)
  pack_in<<<2368, 256, 0, stream>>>(x, w1, w2, P1h, P1l, Q1, Qc1, P2h, P2l, Q2,
                                    Axh, Axl, Wcat, BpAh, BpAl, Z0h, Z0l, out0);

  // D2: compose single-step operators (fat-row tiles, V-hoisted)
  composeK<<<768, 512, 0, stream>>>(P1h, P1l, Q1, P2h, P2l, Q2, Axh, Axl, Qc1,
                                    Vpk1, Wcat, V1pAh, V1pAl, UpAh, UpAl,
                                    Z0h, Z0l, c1Z);

  // D3: combo = seed step + compose2
  {
    IArgs seed{Z0h, Z0l, Z1h, Z1l, Vpk1, Wcat, c1Z, nullptr,
               c1bZ, d2Z, out1, out2, 128};
    C2A c2{V1pAh, V1pAl, UpAh, UpAl, BpAh, BpAl, Vpk1, Wcat, V1sqI, Wcat2};
    combo<<<1472, 512, 0, stream>>>(seed, c2);
  }

  // D4..D12: 9 fused double-steps
  for (int tau = 0; tau < 9; ++tau) {
    const bool odd = tau & 1;
    IArgs ia{odd ? Z0h : Z1h, odd ? Z0l : Z1l,
             odd ? Z1h : Z0h, odd ? Z1l : Z0l,
             V1sqI, Wcat2, c1bZ, d2Z, nullptr, nullptr, out1, out2, 128};
    iter_k<<<192, 512, 0, stream>>>(ia, tau == 8 ? 1 : 0, 0);
  }

  // D13: final single g2 step -> out2
  {
    IArgs ia{Z0h, Z0l, Z1h, Z1l, Vpk1, Wcat, nullptr, nullptr,
             nullptr, nullptr, out1, out2, 0};
    iter_k<<<64, 512, 0, stream>>>(ia, 0, 1);
  }
}